// Round 15
// baseline (1213.681 us; speedup 1.0000x reference)
//
#include <hip/hip_runtime.h>
#include <hip/hip_bf16.h>

// Model: 4-layer Mamba2 TS model. B=32 L=1024 DM=256 DI=512 DST=64 NH=8 HD=64
// DC=4 Q=64 chunks=16 DIP=1160(pad 1280) CONVD=640 PRED=192 CO=21.
// I/O fp32. bf16 MFMA operands, fp32 accum. WS ~236.5 MB.
// R14->R15: SINGLE FIX — conv grid 10368->2592 (8192*81 threads; R14's 10368
// made rt span [0,32768) vs expected [0,8192): b up to 127 -> OOB r/w -> core
// dump). Structure unchanged: R12 BK=64 GEMMs (ledger optimum), dt fused in
// conv (g==80 lane group), outBC reads acbuf (bit-identical to recompute).
// Ledger: dt-in-GEMM-epilogue bad, XCD swizzle bad, A-resident bad, BK=64
// good, pipelined dbuf bad (R13: 48->55.7us).

typedef unsigned short ushort_t;
typedef unsigned int uint_t;
typedef __attribute__((ext_vector_type(8))) short short8;
typedef __attribute__((ext_vector_type(4))) float f32x4;
typedef __attribute__((ext_vector_type(4))) ushort_t ushort4_t;

__device__ __forceinline__ float b2f(ushort_t u) {
    uint_t v = ((uint_t)u) << 16;
    return __builtin_bit_cast(float, v);
}
__device__ __forceinline__ ushort_t f2b(float f) {
    uint_t u = __builtin_bit_cast(uint_t, f);
    uint_t r = (u + 0x7FFFu + ((u >> 16) & 1u)) >> 16;
    return (ushort_t)r;
}
__device__ __forceinline__ float silu_f(float x) {
    return x / (1.f + __expf(-x));
}
__device__ __forceinline__ void gl_lds16(const ushort_t* g, ushort_t* l) {
    __builtin_amdgcn_global_load_lds(
        (const __attribute__((address_space(1))) unsigned int*)g,
        (__attribute__((address_space(3))) unsigned int*)l, 16, 0, 0);
}

// ---------------- weight converts ----------------
__global__ __launch_bounds__(256) void cvt_kernel(const float* __restrict__ in,
        ushort_t* __restrict__ out, int n) {
    int i = blockIdx.x * 256 + threadIdx.x;
    if (i < n) out[i] = f2b(in[i]);
}
// in_proj w: [4][1160][256] -> bf16 [4][1280][256], rows >=1160 zero
__global__ __launch_bounds__(256) void cvt_pad_ip(const float* __restrict__ in,
        ushort_t* __restrict__ out) {
    int i = blockIdx.x * 256 + threadIdx.x;     // < 4*1280*256
    if (i >= 4 * 1280 * 256) return;
    int layer = i / (1280 * 256);
    int rem = i - layer * 1280 * 256;
    int n = rem >> 8, k = rem & 255;
    out[i] = (n < 1160) ? f2b(in[(size_t)layer * 1160 * 256 + n * 256 + k]) : (ushort_t)0;
}
// conv w: [4][640][4] -> [4][4][640] fp32 transpose
__global__ __launch_bounds__(256) void cvt_convw(const float* __restrict__ in,
        float* __restrict__ out) {
    int i = blockIdx.x * 256 + threadIdx.x;     // < 4*2560
    if (i >= 10240) return;
    int layer = i / 2560;
    int rem = i - layer * 2560;
    int k = rem / 640, ch = rem - k * 640;
    out[i] = in[layer * 2560 + ch * 4 + k];
}

// ---------------- pos-emb table: pe[l][d], computed once ----------------
__global__ __launch_bounds__(256) void pe_kernel(float* __restrict__ pe) {
    int l = blockIdx.x, d = threadIdx.x;
    float div = __expf((float)(d & ~1) * (-9.210340371976184f / 256.0f));
    float arg = (float)l * div;
    pe[l * 256 + d] = (d & 1) ? cosf(arg) : sinf(arg);
}

// ---------------- stats ----------------
__global__ __launch_bounds__(256) void stats_kernel(const float* __restrict__ xe,
        float* __restrict__ meanb, float* __restrict__ stdb, float* __restrict__ rstdb) {
    int bi = blockIdx.x;
    int b = bi / 21, c = bi - b * 21;
    int tid = threadIdx.x;
    float s = 0.f, s2 = 0.f;
    for (int l = tid; l < 1024; l += 256) {
        float v = xe[(b * 1024 + l) * 21 + c];
        s += v; s2 += v * v;
    }
    __shared__ float r1[4], r2[4];
    for (int o = 32; o > 0; o >>= 1) { s += __shfl_down(s, o, 64); s2 += __shfl_down(s2, o, 64); }
    if ((tid & 63) == 0) { r1[tid >> 6] = s; r2[tid >> 6] = s2; }
    __syncthreads();
    if (tid == 0) {
        float S = r1[0] + r1[1] + r1[2] + r1[3];
        float S2 = r2[0] + r2[1] + r2[2] + r2[3];
        float m = S * (1.f / 1024.f);
        float var = S2 * (1.f / 1024.f) - m * m;
        float sd = sqrtf(var + 1e-5f);
        meanb[bi] = m; stdb[bi] = sd; rstdb[bi] = 1.f / sd;
    }
}

// ---------------- embedding: sliding-window, tokw in registers ----------------
__global__ __launch_bounds__(256) void embed3_kernel(const float* __restrict__ xe,
        const float* __restrict__ xm, const float* __restrict__ tokw,
        const float* __restrict__ tembw, const float* __restrict__ pe,
        const float* __restrict__ meanb, const float* __restrict__ rstdb,
        float* __restrict__ h, ushort_t* __restrict__ hbf) {
    int blk = blockIdx.x;               // b*16 + tile
    int b = blk >> 4, t = blk & 15;
    int l0 = t * 64;
    int tid = threadIdx.x;              // = d
    __shared__ float xw[66][22];        // normalized x window, row0 = l0-1 (wrap)
    __shared__ float xmw[64][4];
    __shared__ float mn[21], rs[21];
    if (tid < 21) { mn[tid] = meanb[b * 21 + tid]; rs[tid] = rstdb[b * 21 + tid]; }
    float twr[63];
    {
        const float* tp = tokw + tid * 63;
        #pragma unroll
        for (int i = 0; i < 63; i++) twr[i] = tp[i];
    }
    float tbr[4];
    #pragma unroll
    for (int k = 0; k < 4; k++) tbr[k] = tembw[tid * 4 + k];
    __syncthreads();
    for (int i = tid; i < 1386; i += 256) {
        int row = i / 21, c = i - row * 21;
        int gl = (l0 - 1 + row + 1024) & 1023;
        xw[row][c] = (xe[(size_t)(b * 1024 + gl) * 21 + c] - mn[c]) * rs[c];
    }
    {
        int row = tid >> 2, c = tid & 3;
        xmw[row][c] = xm[(size_t)(b * 1024 + l0 + row) * 4 + c];
    }
    __syncthreads();
    int d = tid;
    float acc2 = 0.f, acc1 = 0.f;   // pending partial sums for out[r-2], out[r-1]
    for (int r = 0; r < 66; r++) {
        float s0 = 0.f, s1 = 0.f, s2 = 0.f;
        #pragma unroll
        for (int c = 0; c < 21; c++) {
            float xv = xw[r][c];
            s0 += xv * twr[c * 3 + 0];
            s1 += xv * twr[c * 3 + 1];
            s2 += xv * twr[c * 3 + 2];
        }
        if (r >= 2) {
            int li = r - 2;
            float acc = acc2 + s2 + pe[(size_t)(l0 + li) * 256 + d];
            #pragma unroll
            for (int k = 0; k < 4; k++) acc += xmw[li][k] * tbr[k];
            size_t o = (size_t)(b * 1024 + l0 + li) * 256 + d;
            h[o] = acc;
            hbf[o] = f2b(acc);
        }
        acc2 = acc1 + s1;
        acc1 = s0;
    }
}

// ---------------- 128x128 LDS-staged GEMM mainloop, BK=64 (2x32 panels) ----------------
// R12 structure, measured optimum. MFMA order ascending k -> bit-identical.
template<int KDIM>
__device__ __forceinline__ void gemm128_main(const ushort_t* __restrict__ Ab,
        const ushort_t* __restrict__ Wb, ushort_t* sA, ushort_t* sW,
        f32x4 (&acc)[16], int m0, int n0) {
    int tid = threadIdx.x;
    int w = tid >> 6, lane = tid & 63;
    int wm = w >> 1, wn = w & 1;
    int rr = lane & 15, quad = lane >> 4;
    int srow0 = w * 32 + (lane >> 2);       // staging row (+ j*16)
    int skk = (lane & 3) * 8;               // staging k-offset (shorts)
    int sl0 = w * 1024 + lane * 8;          // staging LDS index (+ j*512, + p*4096)
    for (int k0 = 0; k0 < KDIM; k0 += 64) {
        __syncthreads();                    // prev MFMA reads done before overwrite
        #pragma unroll
        for (int p = 0; p < 2; p++) {
            #pragma unroll
            for (int j = 0; j < 2; j++) {
                int row = srow0 + j * 16;
                int koff = k0 + p * 32 + skk;
                gl_lds16(Ab + (size_t)(m0 + row) * KDIM + koff, &sA[p * 4096 + sl0 + j * 512]);
                gl_lds16(Wb + (size_t)(n0 + row) * KDIM + koff, &sW[p * 4096 + sl0 + j * 512]);
            }
        }
        __syncthreads();                    // compiler drains vmcnt before barrier
        #pragma unroll
        for (int p = 0; p < 2; p++) {
            short8 a[4], b[4];
            #pragma unroll
            for (int i = 0; i < 4; i++)
                a[i] = *(const short8*)&sA[p * 4096 + (wm * 64 + i * 16 + rr) * 32 + quad * 8];
            #pragma unroll
            for (int j = 0; j < 4; j++)
                b[j] = *(const short8*)&sW[p * 4096 + (wn * 64 + j * 16 + rr) * 32 + quad * 8];
            #pragma unroll
            for (int i = 0; i < 4; i++)
                #pragma unroll
                for (int j = 0; j < 4; j++)
                    acc[i * 4 + j] = __builtin_amdgcn_mfma_f32_16x16x32_bf16(a[i], b[j], acc[i * 4 + j], 0, 0, 0);
        }
    }
}

// in_proj: A[32768x256] x W[1280x256] -> split z (n<512) | xBC/dt (512<=n<1160)
__global__ __launch_bounds__(256) void gemm_ip(const ushort_t* __restrict__ A,
        const ushort_t* __restrict__ W, ushort_t* __restrict__ zbuf,
        ushort_t* __restrict__ xbuf) {
    int blk = blockIdx.x;               // 2560 = 256 m-tiles x 10 n-tiles, linear map
    int tm = blk / 10, tn = blk - tm * 10;
    int m0 = tm * 128, n0 = tn * 128;
    __shared__ ushort_t sA[8192], sW[8192];
    f32x4 acc[16];
    #pragma unroll
    for (int i = 0; i < 16; i++) acc[i] = (f32x4){0.f, 0.f, 0.f, 0.f};
    gemm128_main<256>(A, W, sA, sW, acc, m0, n0);
    int lane = threadIdx.x & 63, w = threadIdx.x >> 6;
    int wm = w >> 1, wn = w & 1;
    int rr = lane & 15, quad = lane >> 4;
    #pragma unroll
    for (int i = 0; i < 4; i++) {
        int mrow = m0 + wm * 64 + i * 16 + quad * 4;
        #pragma unroll
        for (int j = 0; j < 4; j++) {
            int n = n0 + wn * 64 + j * 16 + rr;
            #pragma unroll
            for (int r2 = 0; r2 < 4; r2++) {
                ushort_t v = f2b(acc[i * 4 + j][r2]);
                if (n < 512) zbuf[(size_t)(mrow + r2) * 512 + n] = v;
                else if (n < 1160) xbuf[(size_t)(mrow + r2) * 704 + (n - 512)] = v;
            }
        }
    }
}

// out_proj: A[32768x512] x W[256x512] -> C[32768x256] fp32
__global__ __launch_bounds__(256) void gemm_op(const ushort_t* __restrict__ A,
        const ushort_t* __restrict__ W, float* __restrict__ C) {
    int blk = blockIdx.x;               // 512 = 256 m-tiles x 2 n-tiles, linear map
    int tm = blk >> 1, tn = blk & 1;
    int m0 = tm * 128, n0 = tn * 128;
    __shared__ ushort_t sA[8192], sW[8192];
    f32x4 acc[16];
    #pragma unroll
    for (int i = 0; i < 16; i++) acc[i] = (f32x4){0.f, 0.f, 0.f, 0.f};
    gemm128_main<512>(A, W, sA, sW, acc, m0, n0);
    int lane = threadIdx.x & 63, w = threadIdx.x >> 6;
    int wm = w >> 1, wn = w & 1;
    int rr = lane & 15, quad = lane >> 4;
    #pragma unroll
    for (int i = 0; i < 4; i++) {
        int mrow = m0 + wm * 64 + i * 16 + quad * 4;
        #pragma unroll
        for (int j = 0; j < 4; j++) {
            int n = n0 + wn * 64 + j * 16 + rr;
            #pragma unroll
            for (int r2 = 0; r2 < 4; r2++)
                C[(size_t)(mrow + r2) * 256 + n] = acc[i * 4 + j][r2];
        }
    }
}

// ---------------- causal depthwise conv + bias + silu, dt fused (g==80) ----------------
// grid: 8192*81 threads = 2592 blocks (rt in [0,8192) = 32 b x 256 l-tiles)
__global__ __launch_bounds__(256) void conv_kernel(const ushort_t* __restrict__ xbuf,
        const float* __restrict__ cwt, const float* __restrict__ cb,
        const float* __restrict__ dtb, ushort_t* __restrict__ xc,
        float* __restrict__ dts) {
    int idx = blockIdx.x * 256 + threadIdx.x;   // < 8192*81 = 663552
    if (idx >= 663552) return;
    int g = idx % 81;
    int rt = idx / 81;
    int b = rt >> 8;
    int l0 = (rt & 255) << 2;
    if (g == 80) {
        // dt path: softplus(xbuf[row][640..648] + dtb) -> dts[row*8..]
        #pragma unroll
        for (int lo = 0; lo < 4; lo++) {
            int row = b * 1024 + l0 + lo;
            short8 dv = *(const short8*)(xbuf + (size_t)row * 704 + 640);
            #pragma unroll
            for (int j = 0; j < 8; j++) {
                float x = b2f(((ushort_t*)&dv)[j]) + dtb[j];
                dts[(size_t)row * 8 + j] = (x > 20.f) ? x : log1pf(__expf(x));
            }
        }
        return;
    }
    int ch0 = g * 8;
    float wgt[4][8];
    #pragma unroll
    for (int k = 0; k < 4; k++) {
        float4 w0 = *(const float4*)(cwt + k * 640 + ch0);
        float4 w1 = *(const float4*)(cwt + k * 640 + ch0 + 4);
        wgt[k][0] = w0.x; wgt[k][1] = w0.y; wgt[k][2] = w0.z; wgt[k][3] = w0.w;
        wgt[k][4] = w1.x; wgt[k][5] = w1.y; wgt[k][6] = w1.z; wgt[k][7] = w1.w;
    }
    float bias[8];
    {
        float4 b0 = *(const float4*)(cb + ch0);
        float4 b1 = *(const float4*)(cb + ch0 + 4);
        bias[0] = b0.x; bias[1] = b0.y; bias[2] = b0.z; bias[3] = b0.w;
        bias[4] = b1.x; bias[5] = b1.y; bias[6] = b1.z; bias[7] = b1.w;
    }
    short8 xr[7];
    const ushort_t* base = xbuf + (size_t)(b * 1024 + l0) * 704 + ch0;
    #pragma unroll
    for (int i = 0; i < 7; i++) {
        int ll = l0 - 3 + i;
        if (ll >= 0) xr[i] = *(const short8*)(base + (ptrdiff_t)(i - 3) * 704);
        else         xr[i] = (short8){0, 0, 0, 0, 0, 0, 0, 0};
    }
    #pragma unroll
    for (int lo = 0; lo < 4; lo++) {
        float acc[8];
        #pragma unroll
        for (int j = 0; j < 8; j++) acc[j] = bias[j];
        #pragma unroll
        for (int k = 0; k < 4; k++) {
            #pragma unroll
            for (int j = 0; j < 8; j++)
                acc[j] += b2f(((ushort_t*)&xr[lo + k])[j]) * wgt[k][j];
        }
        short8 o;
        #pragma unroll
        for (int j = 0; j < 8; j++) ((ushort_t*)&o)[j] = f2b(silu_f(acc[j]));
        *(short8*)(xc + (size_t)(b * 1024 + l0 + lo) * 640 + ch0) = o;
    }
}

// ---------------- SSD A: chunk states = (B*dec)^T @ X per (b,h,chunk) ----------------
__global__ __launch_bounds__(256) void ssd_stateA(const ushort_t* __restrict__ xc,
        const float* __restrict__ dts, const float* __restrict__ alog,
        float* __restrict__ stbuf, float* __restrict__ acbuf) {
    int idx = blockIdx.x;               // bh*16 + chunk
    int bh = idx >> 4, chunk = idx & 15;
    int b = bh >> 3, h = bh & 7;
    int l0 = chunk * 64;
    float Ah = -__expf(alog[h]);
    int tid = threadIdx.x;
    int q = tid >> 2, pb = (tid & 3) * 16;

    __shared__ ushort_t Bt[64][72], Xt[64][72];
    __shared__ float dec_s[64];

    const ushort_t* xrow = xc + (size_t)(b * 1024 + l0 + q) * 640;
    ushort_t bv[16], xv[16];
    *(short8*)&bv[0] = *(const short8*)(xrow + 512 + pb);
    *(short8*)&bv[8] = *(const short8*)(xrow + 512 + pb + 8);
    *(short8*)&xv[0] = *(const short8*)(xrow + h * 64 + pb);
    *(short8*)&xv[8] = *(const short8*)(xrow + h * 64 + pb + 8);
    #pragma unroll
    for (int j = 0; j < 16; j++) Xt[pb + j][q] = xv[j];

    if (tid < 64) {
        float d = dts[(size_t)(b * 1024 + l0 + tid) * 8 + h];
        float a = d * Ah;
        #pragma unroll
        for (int off = 1; off < 64; off <<= 1) {
            float t = __shfl_up(a, off, 64);
            if (tid >= off) a += t;
        }
        acbuf[(size_t)idx * 64 + tid] = a;
        float tot = __shfl(a, 63, 64);
        dec_s[tid] = __expf(tot - a) * d;
    }
    __syncthreads();
    {
        float dq = dec_s[q];
        #pragma unroll
        for (int j = 0; j < 16; j++) Bt[pb + j][q] = f2b(b2f(bv[j]) * dq);
    }
    __syncthreads();

    int w = tid >> 6, lane = tid & 63;
    int rr = lane & 15, quad = lane >> 4, qb = w * 16;
    f32x4 acc[4];
    #pragma unroll
    for (int t = 0; t < 4; t++) acc[t] = (f32x4){0.f, 0.f, 0.f, 0.f};
    #pragma unroll
    for (int ks = 0; ks < 2; ks++) {
        short8 a = *(const short8*)(&Bt[qb + rr][ks * 32 + quad * 8]);
        #pragma unroll
        for (int t = 0; t < 4; t++) {
            short8 bb = *(const short8*)(&Xt[t * 16 + rr][ks * 32 + quad * 8]);
            acc[t] = __builtin_amdgcn_mfma_f32_16x16x32_bf16(a, bb, acc[t], 0, 0, 0);
        }
    }
    float* sb = stbuf + (size_t)idx * 4096;
    #pragma unroll
    for (int t = 0; t < 4; t++) {
        int p = t * 16 + rr;
        #pragma unroll
        for (int r2 = 0; r2 < 4; r2++) {
            int nn = qb + quad * 4 + r2;
            sb[nn * 64 + p] = acc[t][r2];
        }
    }
}

// ---------------- SSD B: scan chunk states in place (4-way split) ----------------
__global__ __launch_bounds__(256) void ssd_scan(float* __restrict__ stbuf,
        const float* __restrict__ acbuf) {
    int bh = blockIdx.x >> 2, sl = blockIdx.x & 3;
    int tid = threadIdx.x;
    size_t boff = (size_t)sl * 1024 + tid * 4;
    float4 S = make_float4(0.f, 0.f, 0.f, 0.f);
    for (int c = 0; c < 16; c++) {
        float* p = stbuf + ((size_t)bh * 16 + c) * 4096 + boff;
        float ad = __expf(acbuf[((size_t)bh * 16 + c) * 64 + 63]);
        float4 v = *(float4*)p;
        *(float4*)p = S;
        S.x = ad * S.x + v.x; S.y = ad * S.y + v.y;
        S.z = ad * S.z + v.z; S.w = ad * S.w + v.w;
    }
}

// ---------------- SSD C: y = Y_diag + Y_off + D*x -> bf16 ----------------
__global__ __launch_bounds__(256) void ssd_outBC(const ushort_t* __restrict__ xc,
        const float* __restrict__ dts, const float* __restrict__ acbuf,
        const float* __restrict__ dsk, const float* __restrict__ stbuf,
        ushort_t* __restrict__ ybuf) {
    int idx = blockIdx.x;
    int bh = idx >> 4, chunk = idx & 15;
    int b = bh >> 3, h = bh & 7;
    int l0 = chunk * 64;
    float Dh = dsk[h];
    int tid = threadIdx.x;
    int q = tid >> 2, pb = (tid & 3) * 16;

    __shared__ ushort_t Cs[64][72], Bs[64][72], Xt[64][72], Gs[64][72], Shi[64][72], Slo[64][72];
    __shared__ float acum_s[64], dtq_s[64], ea_s[64];

    const ushort_t* xrow = xc + (size_t)(b * 1024 + l0 + q) * 640;
    *(short8*)&Bs[q][pb]     = *(const short8*)(xrow + 512 + pb);
    *(short8*)&Bs[q][pb + 8] = *(const short8*)(xrow + 512 + pb + 8);
    *(short8*)&Cs[q][pb]     = *(const short8*)(xrow + 576 + pb);
    *(short8*)&Cs[q][pb + 8] = *(const short8*)(xrow + 576 + pb + 8);
    ushort_t xv[16];
    *(short8*)&xv[0] = *(const short8*)(xrow + h * 64 + pb);
    *(short8*)&xv[8] = *(const short8*)(xrow + h * 64 + pb + 8);
    #pragma unroll
    for (int j = 0; j < 16; j++) Xt[pb + j][q] = xv[j];
    {
        const float* sp = stbuf + (size_t)idx * 4096 + q * 64 + pb;
        #pragma unroll
        for (int j = 0; j < 16; j++) {
            float s = sp[j];
            ushort_t hi = f2b(s);
            Shi[pb + j][q] = hi;
            Slo[pb + j][q] = f2b(s - b2f(hi));
        }
    }
    if (tid < 64) {
        // acum from stateA's acbuf (bit-identical); no shfl recompute
        float a = acbuf[(size_t)idx * 64 + tid];
        acum_s[tid] = a;
        ea_s[tid] = __expf(a);
        dtq_s[tid] = dts[(size_t)(b * 1024 + l0 + tid) * 8 + h];
    }
    __syncthreads();

    int w = tid >> 6, lane = tid & 63;
    int rr = lane & 15, quad = lane >> 4, qb = w * 16;

    // mm1: G = C.B^T masked -> Gs bf16
    {
        f32x4 g[4];
        #pragma unroll
        for (int t = 0; t < 4; t++) g[t] = (f32x4){0.f, 0.f, 0.f, 0.f};
        #pragma unroll
        for (int ks = 0; ks < 2; ks++) {
            short8 a = *(const short8*)(&Cs[qb + rr][ks * 32 + quad * 8]);
            #pragma unroll
            for (int t = 0; t < 4; t++) {
                short8 bb = *(const short8*)(&Bs[t * 16 + rr][ks * 32 + quad * 8]);
                g[t] = __builtin_amdgcn_mfma_f32_16x16x32_bf16(a, bb, g[t], 0, 0, 0);
            }
        }
        #pragma unroll
        for (int t = 0; t < 4; t++) {
            int s = t * 16 + rr;
            float as = acum_s[s], dss = dtq_s[s];
            #pragma unroll
            for (int r2 = 0; r2 < 4; r2++) {
                int qq = qb + quad * 4 + r2;
                float v = (s <= qq) ? g[t][r2] * __expf(acum_s[qq] - as) * dss : 0.f;
                Gs[qq][s] = f2b(v);
            }
        }
    }
    __syncthreads();

    // mm2: Y_diag = G@X ; Y_off = C@(Shi+Slo)
    f32x4 aD[4], aO[4];
    #pragma unroll
    for (int t = 0; t < 4; t++) { aD[t] = (f32x4){0.f,0.f,0.f,0.f}; aO[t] = (f32x4){0.f,0.f,0.f,0.f}; }
    #pragma unroll
    for (int ks = 0; ks < 2; ks++) {
        short8 ga = *(const short8*)(&Gs[qb + rr][ks * 32 + quad * 8]);
        short8 ca = *(const short8*)(&Cs[qb + rr][ks * 32 + quad * 8]);
        #pragma unroll
        for (int t = 0; t < 4; t++) {
            short8 xb = *(const short8*)(&Xt[t * 16 + rr][ks * 32 + quad * 8]);
            short8 sh = *(const short8*)(&Shi[t * 16 + rr][ks * 32 + quad * 8]);
            short8 sl = *(const short8*)(&Slo[t * 16 + rr][ks * 32 + quad * 8]);
            aD[t] = __builtin_amdgcn_mfma_f32_16x16x32_bf16(ga, xb, aD[t], 0, 0, 0);
            aO[t] = __builtin_amdgcn_mfma_f32_16x16x32_bf16(ca, sh, aO[t], 0, 0, 0);
            aO[t] = __builtin_amdgcn_mfma_f32_16x16x32_bf16(ca, sl, aO[t], 0, 0, 0);
        }
    }
    #pragma unroll
    for (int t = 0; t < 4; t++) {
        int p = t * 16 + rr;
        #pragma unroll
        for (int r2 = 0; r2 < 4; r2++) {
            int qq = qb + quad * 4 + r2;
            float y = aD[t][r2] + ea_s[qq] * aO[t][r2] + Dh * b2f(Xt[p][qq]);
            ybuf[(size_t)(b * 1024 + l0 + qq) * 512 + h * 64 + p] = f2b(y);
        }
    }
}

// ---------------- gate: wave-per-row, 16B/lane ----------------
__global__ __launch_bounds__(256) void gate_kernel(const ushort_t* __restrict__ zbuf,
        ushort_t* __restrict__ ybuf, const float* __restrict__ gw) {
    int row = blockIdx.x * 4 + (threadIdx.x >> 6);
    int lane = threadIdx.x & 63;
    size_t base = (size_t)row * 512 + lane * 8;
    short8 zv = *(const short8*)(zbuf + base);
    short8 yv = *(const short8*)(ybuf + base);
    float v[8];
    float ss = 0.f;
    #pragma unroll
    for (int j = 0; j < 8; j++) {
        v[j] = b2f(((ushort_t*)&yv)[j]) * silu_f(b2f(((ushort_t*)&zv)[j]));
        ss += v[j] * v[j];
    }
    #pragma unroll
    for (int o = 1; o < 64; o <<= 1) ss += __shfl_xor(ss, o, 64);
    float rms = rsqrtf(ss * (1.f / 512.f) + 1e-5f);
    float4 g0 = *(const float4*)(gw + lane * 8);
    float4 g1 = *(const float4*)(gw + lane * 8 + 4);
    float gv[8] = {g0.x, g0.y, g0.z, g0.w, g1.x, g1.y, g1.z, g1.w};
    short8 o;
    #pragma unroll
    for (int j = 0; j < 8; j++) ((ushort_t*)&o)[j] = f2b(v[j] * rms * gv[j]);
    *(short8*)(ybuf + base) = o;
}

// ---------------- residual + layernorm: wave-per-row, 16B/lane ----------------
__global__ __launch_bounds__(256) void resln_kernel(float* __restrict__ h,
        ushort_t* __restrict__ hbf, const float* __restrict__ yp,
        const float* __restrict__ g, const float* __restrict__ bb) {
    int row = blockIdx.x * 4 + (threadIdx.x >> 6);
    int lane = threadIdx.x & 63;
    size_t base = (size_t)row * 256 + lane * 4;
    float4 hv = *(const float4*)(h + base);
    float4 yv = *(const float4*)(yp + base);
    float x[4] = {hv.x + yv.x, hv.y + yv.y, hv.z + yv.z, hv.w + yv.w};
    float s = 0.f, s2 = 0.f;
    #pragma unroll
    for (int j = 0; j < 4; j++) { s += x[j]; s2 += x[j] * x[j]; }
    #pragma unroll
    for (int o = 1; o < 64; o <<= 1) { s += __shfl_xor(s, o, 64); s2 += __shfl_xor(s2, o, 64); }
    float mu = s * (1.f / 256.f);
    float var = s2 * (1.f / 256.f) - mu * mu;
    float rstd = rsqrtf(var + 1e-5f);
    float4 gv = *(const float4*)(g + lane * 4);
    float4 bv = *(const float4*)(bb + lane * 4);
    float gr[4] = {gv.x, gv.y, gv.z, gv.w};
    float br[4] = {bv.x, bv.y, bv.z, bv.w};
    float4 ho;
    ushort4_t bo;
    #pragma unroll
    for (int j = 0; j < 4; j++) {
        float o = (x[j] - mu) * rstd * gr[j] + br[j];
        ((float*)&ho)[j] = o;
        bo[j] = f2b(o);
    }
    *(float4*)(h + base) = ho;
    *(ushort4_t*)(hbf + base) = bo;
}

// ---------------- head ----------------
__global__ __launch_bounds__(256) void head_kernel(const float* __restrict__ h,
        const float* __restrict__ hw, const float* __restrict__ stdb,
        const float* __restrict__ meanb, float* __restrict__ out) {
    int blk = blockIdx.x;       // b*192 + t
    int b = blk / 192, t = blk - b * 192;
    int l = 832 + t;
    int tid = threadIdx.x;
    __shared__ float hr[256];
    hr[tid] = h[(size_t)(b * 1024 + l) * 256 + tid];
    __syncthreads();
    if (tid < 21) {
        float acc = 0.f;
        for (int k = 0; k < 256; k++) acc += hr[k] * hw[tid * 256 + k];
        out[(size_t)blk * 21 + tid] = acc * stdb[b * 21 + tid] + meanb[b * 21 + tid];
    }
}

extern "C" void kernel_launch(void* const* d_in, const int* in_sizes, int n_in,
                              void* d_out, int out_size, void* d_ws, size_t ws_size,
                              hipStream_t stream) {
    const float* x_enc  = (const float*)d_in[0];
    const float* x_mark = (const float*)d_in[1];
    const float* tokw   = (const float*)d_in[4];
    const float* tembw  = (const float*)d_in[5];
    const float* ln_g   = (const float*)d_in[6];
    const float* ln_b   = (const float*)d_in[7];
    const float* ipw    = (const float*)d_in[8];
    const float* cw     = (const float*)d_in[9];
    const float* cb     = (const float*)d_in[10];
    const float* dtb    = (const float*)d_in[11];
    const float* alog   = (const float*)d_in[12];
    const float* dsk    = (const float*)d_in[13];
    const float* gw     = (const float*)d_in[14];
    const float* opw    = (const float*)d_in[15];
    const float* hw     = (const float*)d_in[16];
    float* out = (float*)d_out;

    char* w = (char*)d_ws;
    size_t off = 0;
    auto alloc = [&](size_t bytes) -> void* {
        void* p = w + off;
        off += (bytes + 255) & ~(size_t)255;
        return p;
    };
    float* meanb  = (float*)alloc(672 * 4);
    float* stdb   = (float*)alloc(672 * 4);
    float* rstdb  = (float*)alloc(672 * 4);
    float* dts    = (float*)alloc((size_t)262144 * 4);            // 1.05 MB
    float* pebuf  = (float*)alloc((size_t)262144 * 4);            // 1.05 MB
    float* cwt    = (float*)alloc((size_t)10240 * 4);             // 40 KB
    float* hbuf   = (float*)alloc((size_t)8388608 * 4);           // 33.55 MB
    ushort_t* hbf = (ushort_t*)alloc((size_t)8388608 * 2);        // 16.78 MB
    ushort_t* zbuf= (ushort_t*)alloc((size_t)32768 * 512 * 2);    // 33.55 MB
    ushort_t* xc  = (ushort_t*)alloc((size_t)32768 * 640 * 2);    // 41.94 MB
    char* R       = (char*)alloc((size_t)71303168);               // 71.30 MB union
    ushort_t* ybuf= (ushort_t*)alloc((size_t)32768 * 512 * 2);    // 33.55 MB
    ushort_t* wipb= (ushort_t*)alloc((size_t)4 * 1280 * 256 * 2); // 2.62 MB
    ushort_t* wopb= (ushort_t*)alloc((size_t)4 * 256 * 512 * 2);  // 1.05 MB
    // region R aliases: xbuf (gemm_ip out) dies after conv(+dt); stbuf/acbuf take over
    ushort_t* xbuf = (ushort_t*)R;                        // 32768 x 704 bf16 = 46.14 MB
    float* stbuf   = (float*)R;                           // 256*16*4096 fp32 = 67.11 MB
    float* acbuf   = (float*)(R + 67108864);              // 256*16*64 fp32 = 4.19 MB
    float* yproj   = (float*)xc;                          // alias: xc dead once gemm_op runs
    (void)ws_size; (void)in_sizes; (void)n_in; (void)out_size;
    // total ~236.5 MB

    stats_kernel<<<672, 256, 0, stream>>>(x_enc, meanb, stdb, rstdb);
    pe_kernel<<<1024, 256, 0, stream>>>(pebuf);
    cvt_pad_ip<<<5120, 256, 0, stream>>>(ipw, wipb);
    cvt_kernel<<<2048, 256, 0, stream>>>(opw, wopb, 524288);
    cvt_convw<<<40, 256, 0, stream>>>(cw, cwt);
    embed3_kernel<<<512, 256, 0, stream>>>(x_enc, x_mark, tokw, tembw, pebuf,
                                           meanb, rstdb, hbuf, hbf);

    for (int layer = 0; layer < 4; layer++) {
        // in_proj: 2560 blocks, linear map, BK=64 (R12 optimum)
        gemm_ip<<<2560, 256, 0, stream>>>(hbf, wipb + (size_t)layer * 1280 * 256,
                                          zbuf, xbuf);
        // conv + fused dt: 8192*81 = 663552 threads -> 2592 blocks
        conv_kernel<<<2592, 256, 0, stream>>>(xbuf, cwt + layer * 2560,
                                              cb + layer * 640, dtb + layer * 8,
                                              xc, dts);
        // xbuf now dead -> stbuf/acbuf overwrite region R
        ssd_stateA<<<4096, 256, 0, stream>>>(xc, dts, alog + layer * 8, stbuf, acbuf);
        ssd_scan<<<1024, 256, 0, stream>>>(stbuf, acbuf);
        ssd_outBC<<<4096, 256, 0, stream>>>(xc, dts, acbuf, dsk + layer * 8,
                                            stbuf, ybuf);
        gate_kernel<<<8192, 256, 0, stream>>>(zbuf, ybuf, gw + layer * 512);
        // out_proj: 512 blocks, linear map, BK=64
        gemm_op<<<512, 256, 0, stream>>>(ybuf, wopb + (size_t)layer * 256 * 512, yproj);
        resln_kernel<<<8192, 256, 0, stream>>>(hbuf, hbf, yproj,
                                               ln_g + layer * 256, ln_b + layer * 256);
    }

    head_kernel<<<6144, 256, 0, stream>>>(hbuf, hw, stdb, meanb, out);
}

// Round 16
// 934.429 us; speedup vs baseline: 1.2988x; 1.2988x over previous
//
#include <hip/hip_runtime.h>
#include <hip/hip_bf16.h>

// Model: 4-layer Mamba2 TS model. B=32 L=1024 DM=256 DI=512 DST=64 NH=8 HD=64
// DC=4 Q=64 chunks=16 DIP=1160(pad 1280) CONVD=640 PRED=192 CO=21.
// I/O fp32. bf16 MFMA operands, fp32 accum. WS ~236.5 MB.
// R15->R16: REVERT conv/dt fusion (R15: conv 30->100us, VALUBusy 63% — the
// g==80 dt lane in each wave forced serial execution of 32 libm log1pf
// sequences for the whole wave; divergence killed it). Back to R12's
// standalone conv + dt_kernel. KEEP outBC acbuf reuse (orthogonal, removes
// redundant shfl scan, bit-identical).
// Ledger: dt-in-GEMM bad, dt-in-conv bad (divergence), XCD swizzle bad,
// A-resident bad, BK=64 good (R12=938.8us best), pipelined dbuf bad.

typedef unsigned short ushort_t;
typedef unsigned int uint_t;
typedef __attribute__((ext_vector_type(8))) short short8;
typedef __attribute__((ext_vector_type(4))) float f32x4;
typedef __attribute__((ext_vector_type(4))) ushort_t ushort4_t;

__device__ __forceinline__ float b2f(ushort_t u) {
    uint_t v = ((uint_t)u) << 16;
    return __builtin_bit_cast(float, v);
}
__device__ __forceinline__ ushort_t f2b(float f) {
    uint_t u = __builtin_bit_cast(uint_t, f);
    uint_t r = (u + 0x7FFFu + ((u >> 16) & 1u)) >> 16;
    return (ushort_t)r;
}
__device__ __forceinline__ float silu_f(float x) {
    return x / (1.f + __expf(-x));
}
__device__ __forceinline__ void gl_lds16(const ushort_t* g, ushort_t* l) {
    __builtin_amdgcn_global_load_lds(
        (const __attribute__((address_space(1))) unsigned int*)g,
        (__attribute__((address_space(3))) unsigned int*)l, 16, 0, 0);
}

// ---------------- weight converts ----------------
__global__ __launch_bounds__(256) void cvt_kernel(const float* __restrict__ in,
        ushort_t* __restrict__ out, int n) {
    int i = blockIdx.x * 256 + threadIdx.x;
    if (i < n) out[i] = f2b(in[i]);
}
// in_proj w: [4][1160][256] -> bf16 [4][1280][256], rows >=1160 zero
__global__ __launch_bounds__(256) void cvt_pad_ip(const float* __restrict__ in,
        ushort_t* __restrict__ out) {
    int i = blockIdx.x * 256 + threadIdx.x;     // < 4*1280*256
    if (i >= 4 * 1280 * 256) return;
    int layer = i / (1280 * 256);
    int rem = i - layer * 1280 * 256;
    int n = rem >> 8, k = rem & 255;
    out[i] = (n < 1160) ? f2b(in[(size_t)layer * 1160 * 256 + n * 256 + k]) : (ushort_t)0;
}
// conv w: [4][640][4] -> [4][4][640] fp32 transpose
__global__ __launch_bounds__(256) void cvt_convw(const float* __restrict__ in,
        float* __restrict__ out) {
    int i = blockIdx.x * 256 + threadIdx.x;     // < 4*2560
    if (i >= 10240) return;
    int layer = i / 2560;
    int rem = i - layer * 2560;
    int k = rem / 640, ch = rem - k * 640;
    out[i] = in[layer * 2560 + ch * 4 + k];
}

// ---------------- pos-emb table: pe[l][d], computed once ----------------
__global__ __launch_bounds__(256) void pe_kernel(float* __restrict__ pe) {
    int l = blockIdx.x, d = threadIdx.x;
    float div = __expf((float)(d & ~1) * (-9.210340371976184f / 256.0f));
    float arg = (float)l * div;
    pe[l * 256 + d] = (d & 1) ? cosf(arg) : sinf(arg);
}

// ---------------- stats ----------------
__global__ __launch_bounds__(256) void stats_kernel(const float* __restrict__ xe,
        float* __restrict__ meanb, float* __restrict__ stdb, float* __restrict__ rstdb) {
    int bi = blockIdx.x;
    int b = bi / 21, c = bi - b * 21;
    int tid = threadIdx.x;
    float s = 0.f, s2 = 0.f;
    for (int l = tid; l < 1024; l += 256) {
        float v = xe[(b * 1024 + l) * 21 + c];
        s += v; s2 += v * v;
    }
    __shared__ float r1[4], r2[4];
    for (int o = 32; o > 0; o >>= 1) { s += __shfl_down(s, o, 64); s2 += __shfl_down(s2, o, 64); }
    if ((tid & 63) == 0) { r1[tid >> 6] = s; r2[tid >> 6] = s2; }
    __syncthreads();
    if (tid == 0) {
        float S = r1[0] + r1[1] + r1[2] + r1[3];
        float S2 = r2[0] + r2[1] + r2[2] + r2[3];
        float m = S * (1.f / 1024.f);
        float var = S2 * (1.f / 1024.f) - m * m;
        float sd = sqrtf(var + 1e-5f);
        meanb[bi] = m; stdb[bi] = sd; rstdb[bi] = 1.f / sd;
    }
}

// ---------------- embedding: sliding-window, tokw in registers ----------------
__global__ __launch_bounds__(256) void embed3_kernel(const float* __restrict__ xe,
        const float* __restrict__ xm, const float* __restrict__ tokw,
        const float* __restrict__ tembw, const float* __restrict__ pe,
        const float* __restrict__ meanb, const float* __restrict__ rstdb,
        float* __restrict__ h, ushort_t* __restrict__ hbf) {
    int blk = blockIdx.x;               // b*16 + tile
    int b = blk >> 4, t = blk & 15;
    int l0 = t * 64;
    int tid = threadIdx.x;              // = d
    __shared__ float xw[66][22];        // normalized x window, row0 = l0-1 (wrap)
    __shared__ float xmw[64][4];
    __shared__ float mn[21], rs[21];
    if (tid < 21) { mn[tid] = meanb[b * 21 + tid]; rs[tid] = rstdb[b * 21 + tid]; }
    float twr[63];
    {
        const float* tp = tokw + tid * 63;
        #pragma unroll
        for (int i = 0; i < 63; i++) twr[i] = tp[i];
    }
    float tbr[4];
    #pragma unroll
    for (int k = 0; k < 4; k++) tbr[k] = tembw[tid * 4 + k];
    __syncthreads();
    for (int i = tid; i < 1386; i += 256) {
        int row = i / 21, c = i - row * 21;
        int gl = (l0 - 1 + row + 1024) & 1023;
        xw[row][c] = (xe[(size_t)(b * 1024 + gl) * 21 + c] - mn[c]) * rs[c];
    }
    {
        int row = tid >> 2, c = tid & 3;
        xmw[row][c] = xm[(size_t)(b * 1024 + l0 + row) * 4 + c];
    }
    __syncthreads();
    int d = tid;
    float acc2 = 0.f, acc1 = 0.f;   // pending partial sums for out[r-2], out[r-1]
    for (int r = 0; r < 66; r++) {
        float s0 = 0.f, s1 = 0.f, s2 = 0.f;
        #pragma unroll
        for (int c = 0; c < 21; c++) {
            float xv = xw[r][c];
            s0 += xv * twr[c * 3 + 0];
            s1 += xv * twr[c * 3 + 1];
            s2 += xv * twr[c * 3 + 2];
        }
        if (r >= 2) {
            int li = r - 2;
            float acc = acc2 + s2 + pe[(size_t)(l0 + li) * 256 + d];
            #pragma unroll
            for (int k = 0; k < 4; k++) acc += xmw[li][k] * tbr[k];
            size_t o = (size_t)(b * 1024 + l0 + li) * 256 + d;
            h[o] = acc;
            hbf[o] = f2b(acc);
        }
        acc2 = acc1 + s1;
        acc1 = s0;
    }
}

// ---------------- 128x128 LDS-staged GEMM mainloop, BK=64 (2x32 panels) ----------------
// R12 structure, measured optimum. MFMA order ascending k -> bit-identical.
template<int KDIM>
__device__ __forceinline__ void gemm128_main(const ushort_t* __restrict__ Ab,
        const ushort_t* __restrict__ Wb, ushort_t* sA, ushort_t* sW,
        f32x4 (&acc)[16], int m0, int n0) {
    int tid = threadIdx.x;
    int w = tid >> 6, lane = tid & 63;
    int wm = w >> 1, wn = w & 1;
    int rr = lane & 15, quad = lane >> 4;
    int srow0 = w * 32 + (lane >> 2);       // staging row (+ j*16)
    int skk = (lane & 3) * 8;               // staging k-offset (shorts)
    int sl0 = w * 1024 + lane * 8;          // staging LDS index (+ j*512, + p*4096)
    for (int k0 = 0; k0 < KDIM; k0 += 64) {
        __syncthreads();                    // prev MFMA reads done before overwrite
        #pragma unroll
        for (int p = 0; p < 2; p++) {
            #pragma unroll
            for (int j = 0; j < 2; j++) {
                int row = srow0 + j * 16;
                int koff = k0 + p * 32 + skk;
                gl_lds16(Ab + (size_t)(m0 + row) * KDIM + koff, &sA[p * 4096 + sl0 + j * 512]);
                gl_lds16(Wb + (size_t)(n0 + row) * KDIM + koff, &sW[p * 4096 + sl0 + j * 512]);
            }
        }
        __syncthreads();                    // compiler drains vmcnt before barrier
        #pragma unroll
        for (int p = 0; p < 2; p++) {
            short8 a[4], b[4];
            #pragma unroll
            for (int i = 0; i < 4; i++)
                a[i] = *(const short8*)&sA[p * 4096 + (wm * 64 + i * 16 + rr) * 32 + quad * 8];
            #pragma unroll
            for (int j = 0; j < 4; j++)
                b[j] = *(const short8*)&sW[p * 4096 + (wn * 64 + j * 16 + rr) * 32 + quad * 8];
            #pragma unroll
            for (int i = 0; i < 4; i++)
                #pragma unroll
                for (int j = 0; j < 4; j++)
                    acc[i * 4 + j] = __builtin_amdgcn_mfma_f32_16x16x32_bf16(a[i], b[j], acc[i * 4 + j], 0, 0, 0);
        }
    }
}

// in_proj: A[32768x256] x W[1280x256] -> split z (n<512) | xBC/dt (512<=n<1160)
__global__ __launch_bounds__(256) void gemm_ip(const ushort_t* __restrict__ A,
        const ushort_t* __restrict__ W, ushort_t* __restrict__ zbuf,
        ushort_t* __restrict__ xbuf) {
    int blk = blockIdx.x;               // 2560 = 256 m-tiles x 10 n-tiles, linear map
    int tm = blk / 10, tn = blk - tm * 10;
    int m0 = tm * 128, n0 = tn * 128;
    __shared__ ushort_t sA[8192], sW[8192];
    f32x4 acc[16];
    #pragma unroll
    for (int i = 0; i < 16; i++) acc[i] = (f32x4){0.f, 0.f, 0.f, 0.f};
    gemm128_main<256>(A, W, sA, sW, acc, m0, n0);
    int lane = threadIdx.x & 63, w = threadIdx.x >> 6;
    int wm = w >> 1, wn = w & 1;
    int rr = lane & 15, quad = lane >> 4;
    #pragma unroll
    for (int i = 0; i < 4; i++) {
        int mrow = m0 + wm * 64 + i * 16 + quad * 4;
        #pragma unroll
        for (int j = 0; j < 4; j++) {
            int n = n0 + wn * 64 + j * 16 + rr;
            #pragma unroll
            for (int r2 = 0; r2 < 4; r2++) {
                ushort_t v = f2b(acc[i * 4 + j][r2]);
                if (n < 512) zbuf[(size_t)(mrow + r2) * 512 + n] = v;
                else if (n < 1160) xbuf[(size_t)(mrow + r2) * 704 + (n - 512)] = v;
            }
        }
    }
}

// out_proj: A[32768x512] x W[256x512] -> C[32768x256] fp32
__global__ __launch_bounds__(256) void gemm_op(const ushort_t* __restrict__ A,
        const ushort_t* __restrict__ W, float* __restrict__ C) {
    int blk = blockIdx.x;               // 512 = 256 m-tiles x 2 n-tiles, linear map
    int tm = blk >> 1, tn = blk & 1;
    int m0 = tm * 128, n0 = tn * 128;
    __shared__ ushort_t sA[8192], sW[8192];
    f32x4 acc[16];
    #pragma unroll
    for (int i = 0; i < 16; i++) acc[i] = (f32x4){0.f, 0.f, 0.f, 0.f};
    gemm128_main<512>(A, W, sA, sW, acc, m0, n0);
    int lane = threadIdx.x & 63, w = threadIdx.x >> 6;
    int wm = w >> 1, wn = w & 1;
    int rr = lane & 15, quad = lane >> 4;
    #pragma unroll
    for (int i = 0; i < 4; i++) {
        int mrow = m0 + wm * 64 + i * 16 + quad * 4;
        #pragma unroll
        for (int j = 0; j < 4; j++) {
            int n = n0 + wn * 64 + j * 16 + rr;
            #pragma unroll
            for (int r2 = 0; r2 < 4; r2++)
                C[(size_t)(mrow + r2) * 256 + n] = acc[i * 4 + j][r2];
        }
    }
}

// ---------------- causal depthwise conv + bias + silu (R12 form) ----------------
__global__ __launch_bounds__(256) void conv_kernel(const ushort_t* __restrict__ xbuf,
        const float* __restrict__ cwt, const float* __restrict__ cb,
        ushort_t* __restrict__ xc) {
    int idx = blockIdx.x * 256 + threadIdx.x;   // < 8192*80
    int g = idx % 80;
    int rt = idx / 80;
    int ch0 = g * 8;
    int b = rt >> 8;
    int l0 = (rt & 255) << 2;
    float wgt[4][8];
    #pragma unroll
    for (int k = 0; k < 4; k++) {
        float4 w0 = *(const float4*)(cwt + k * 640 + ch0);
        float4 w1 = *(const float4*)(cwt + k * 640 + ch0 + 4);
        wgt[k][0] = w0.x; wgt[k][1] = w0.y; wgt[k][2] = w0.z; wgt[k][3] = w0.w;
        wgt[k][4] = w1.x; wgt[k][5] = w1.y; wgt[k][6] = w1.z; wgt[k][7] = w1.w;
    }
    float bias[8];
    {
        float4 b0 = *(const float4*)(cb + ch0);
        float4 b1 = *(const float4*)(cb + ch0 + 4);
        bias[0] = b0.x; bias[1] = b0.y; bias[2] = b0.z; bias[3] = b0.w;
        bias[4] = b1.x; bias[5] = b1.y; bias[6] = b1.z; bias[7] = b1.w;
    }
    short8 xr[7];
    const ushort_t* base = xbuf + (size_t)(b * 1024 + l0) * 704 + ch0;
    #pragma unroll
    for (int i = 0; i < 7; i++) {
        int ll = l0 - 3 + i;
        if (ll >= 0) xr[i] = *(const short8*)(base + (ptrdiff_t)(i - 3) * 704);
        else         xr[i] = (short8){0, 0, 0, 0, 0, 0, 0, 0};
    }
    #pragma unroll
    for (int lo = 0; lo < 4; lo++) {
        float acc[8];
        #pragma unroll
        for (int j = 0; j < 8; j++) acc[j] = bias[j];
        #pragma unroll
        for (int k = 0; k < 4; k++) {
            #pragma unroll
            for (int j = 0; j < 8; j++)
                acc[j] += b2f(((ushort_t*)&xr[lo + k])[j]) * wgt[k][j];
        }
        short8 o;
        #pragma unroll
        for (int j = 0; j < 8; j++) ((ushort_t*)&o)[j] = f2b(silu_f(acc[j]));
        *(short8*)(xc + (size_t)(b * 1024 + l0 + lo) * 640 + ch0) = o;
    }
}

// ---------------- dt = softplus(dt_raw + bias) ----------------
__global__ __launch_bounds__(256) void dt_kernel(const ushort_t* __restrict__ xbuf,
        const float* __restrict__ dtb, float* __restrict__ dts) {
    int idx = blockIdx.x * 256 + threadIdx.x;   // < 262144
    int r = idx >> 3, hh = idx & 7;
    float x = b2f(xbuf[(size_t)r * 704 + 640 + hh]) + dtb[hh];
    dts[idx] = (x > 20.f) ? x : log1pf(__expf(x));
}

// ---------------- SSD A: chunk states = (B*dec)^T @ X per (b,h,chunk) ----------------
__global__ __launch_bounds__(256) void ssd_stateA(const ushort_t* __restrict__ xc,
        const float* __restrict__ dts, const float* __restrict__ alog,
        float* __restrict__ stbuf, float* __restrict__ acbuf) {
    int idx = blockIdx.x;               // bh*16 + chunk
    int bh = idx >> 4, chunk = idx & 15;
    int b = bh >> 3, h = bh & 7;
    int l0 = chunk * 64;
    float Ah = -__expf(alog[h]);
    int tid = threadIdx.x;
    int q = tid >> 2, pb = (tid & 3) * 16;

    __shared__ ushort_t Bt[64][72], Xt[64][72];
    __shared__ float dec_s[64];

    const ushort_t* xrow = xc + (size_t)(b * 1024 + l0 + q) * 640;
    ushort_t bv[16], xv[16];
    *(short8*)&bv[0] = *(const short8*)(xrow + 512 + pb);
    *(short8*)&bv[8] = *(const short8*)(xrow + 512 + pb + 8);
    *(short8*)&xv[0] = *(const short8*)(xrow + h * 64 + pb);
    *(short8*)&xv[8] = *(const short8*)(xrow + h * 64 + pb + 8);
    #pragma unroll
    for (int j = 0; j < 16; j++) Xt[pb + j][q] = xv[j];

    if (tid < 64) {
        float d = dts[(size_t)(b * 1024 + l0 + tid) * 8 + h];
        float a = d * Ah;
        #pragma unroll
        for (int off = 1; off < 64; off <<= 1) {
            float t = __shfl_up(a, off, 64);
            if (tid >= off) a += t;
        }
        acbuf[(size_t)idx * 64 + tid] = a;
        float tot = __shfl(a, 63, 64);
        dec_s[tid] = __expf(tot - a) * d;
    }
    __syncthreads();
    {
        float dq = dec_s[q];
        #pragma unroll
        for (int j = 0; j < 16; j++) Bt[pb + j][q] = f2b(b2f(bv[j]) * dq);
    }
    __syncthreads();

    int w = tid >> 6, lane = tid & 63;
    int rr = lane & 15, quad = lane >> 4, qb = w * 16;
    f32x4 acc[4];
    #pragma unroll
    for (int t = 0; t < 4; t++) acc[t] = (f32x4){0.f, 0.f, 0.f, 0.f};
    #pragma unroll
    for (int ks = 0; ks < 2; ks++) {
        short8 a = *(const short8*)(&Bt[qb + rr][ks * 32 + quad * 8]);
        #pragma unroll
        for (int t = 0; t < 4; t++) {
            short8 bb = *(const short8*)(&Xt[t * 16 + rr][ks * 32 + quad * 8]);
            acc[t] = __builtin_amdgcn_mfma_f32_16x16x32_bf16(a, bb, acc[t], 0, 0, 0);
        }
    }
    float* sb = stbuf + (size_t)idx * 4096;
    #pragma unroll
    for (int t = 0; t < 4; t++) {
        int p = t * 16 + rr;
        #pragma unroll
        for (int r2 = 0; r2 < 4; r2++) {
            int nn = qb + quad * 4 + r2;
            sb[nn * 64 + p] = acc[t][r2];
        }
    }
}

// ---------------- SSD B: scan chunk states in place (4-way split) ----------------
__global__ __launch_bounds__(256) void ssd_scan(float* __restrict__ stbuf,
        const float* __restrict__ acbuf) {
    int bh = blockIdx.x >> 2, sl = blockIdx.x & 3;
    int tid = threadIdx.x;
    size_t boff = (size_t)sl * 1024 + tid * 4;
    float4 S = make_float4(0.f, 0.f, 0.f, 0.f);
    for (int c = 0; c < 16; c++) {
        float* p = stbuf + ((size_t)bh * 16 + c) * 4096 + boff;
        float ad = __expf(acbuf[((size_t)bh * 16 + c) * 64 + 63]);
        float4 v = *(float4*)p;
        *(float4*)p = S;
        S.x = ad * S.x + v.x; S.y = ad * S.y + v.y;
        S.z = ad * S.z + v.z; S.w = ad * S.w + v.w;
    }
}

// ---------------- SSD C: y = Y_diag + Y_off + D*x -> bf16 ----------------
__global__ __launch_bounds__(256) void ssd_outBC(const ushort_t* __restrict__ xc,
        const float* __restrict__ dts, const float* __restrict__ acbuf,
        const float* __restrict__ dsk, const float* __restrict__ stbuf,
        ushort_t* __restrict__ ybuf) {
    int idx = blockIdx.x;
    int bh = idx >> 4, chunk = idx & 15;
    int b = bh >> 3, h = bh & 7;
    int l0 = chunk * 64;
    float Dh = dsk[h];
    int tid = threadIdx.x;
    int q = tid >> 2, pb = (tid & 3) * 16;

    __shared__ ushort_t Cs[64][72], Bs[64][72], Xt[64][72], Gs[64][72], Shi[64][72], Slo[64][72];
    __shared__ float acum_s[64], dtq_s[64], ea_s[64];

    const ushort_t* xrow = xc + (size_t)(b * 1024 + l0 + q) * 640;
    *(short8*)&Bs[q][pb]     = *(const short8*)(xrow + 512 + pb);
    *(short8*)&Bs[q][pb + 8] = *(const short8*)(xrow + 512 + pb + 8);
    *(short8*)&Cs[q][pb]     = *(const short8*)(xrow + 576 + pb);
    *(short8*)&Cs[q][pb + 8] = *(const short8*)(xrow + 576 + pb + 8);
    ushort_t xv[16];
    *(short8*)&xv[0] = *(const short8*)(xrow + h * 64 + pb);
    *(short8*)&xv[8] = *(const short8*)(xrow + h * 64 + pb + 8);
    #pragma unroll
    for (int j = 0; j < 16; j++) Xt[pb + j][q] = xv[j];
    {
        const float* sp = stbuf + (size_t)idx * 4096 + q * 64 + pb;
        #pragma unroll
        for (int j = 0; j < 16; j++) {
            float s = sp[j];
            ushort_t hi = f2b(s);
            Shi[pb + j][q] = hi;
            Slo[pb + j][q] = f2b(s - b2f(hi));
        }
    }
    if (tid < 64) {
        // acum from stateA's acbuf (bit-identical); no shfl recompute
        float a = acbuf[(size_t)idx * 64 + tid];
        acum_s[tid] = a;
        ea_s[tid] = __expf(a);
        dtq_s[tid] = dts[(size_t)(b * 1024 + l0 + tid) * 8 + h];
    }
    __syncthreads();

    int w = tid >> 6, lane = tid & 63;
    int rr = lane & 15, quad = lane >> 4, qb = w * 16;

    // mm1: G = C.B^T masked -> Gs bf16
    {
        f32x4 g[4];
        #pragma unroll
        for (int t = 0; t < 4; t++) g[t] = (f32x4){0.f, 0.f, 0.f, 0.f};
        #pragma unroll
        for (int ks = 0; ks < 2; ks++) {
            short8 a = *(const short8*)(&Cs[qb + rr][ks * 32 + quad * 8]);
            #pragma unroll
            for (int t = 0; t < 4; t++) {
                short8 bb = *(const short8*)(&Bs[t * 16 + rr][ks * 32 + quad * 8]);
                g[t] = __builtin_amdgcn_mfma_f32_16x16x32_bf16(a, bb, g[t], 0, 0, 0);
            }
        }
        #pragma unroll
        for (int t = 0; t < 4; t++) {
            int s = t * 16 + rr;
            float as = acum_s[s], dss = dtq_s[s];
            #pragma unroll
            for (int r2 = 0; r2 < 4; r2++) {
                int qq = qb + quad * 4 + r2;
                float v = (s <= qq) ? g[t][r2] * __expf(acum_s[qq] - as) * dss : 0.f;
                Gs[qq][s] = f2b(v);
            }
        }
    }
    __syncthreads();

    // mm2: Y_diag = G@X ; Y_off = C@(Shi+Slo)
    f32x4 aD[4], aO[4];
    #pragma unroll
    for (int t = 0; t < 4; t++) { aD[t] = (f32x4){0.f,0.f,0.f,0.f}; aO[t] = (f32x4){0.f,0.f,0.f,0.f}; }
    #pragma unroll
    for (int ks = 0; ks < 2; ks++) {
        short8 ga = *(const short8*)(&Gs[qb + rr][ks * 32 + quad * 8]);
        short8 ca = *(const short8*)(&Cs[qb + rr][ks * 32 + quad * 8]);
        #pragma unroll
        for (int t = 0; t < 4; t++) {
            short8 xb = *(const short8*)(&Xt[t * 16 + rr][ks * 32 + quad * 8]);
            short8 sh = *(const short8*)(&Shi[t * 16 + rr][ks * 32 + quad * 8]);
            short8 sl = *(const short8*)(&Slo[t * 16 + rr][ks * 32 + quad * 8]);
            aD[t] = __builtin_amdgcn_mfma_f32_16x16x32_bf16(ga, xb, aD[t], 0, 0, 0);
            aO[t] = __builtin_amdgcn_mfma_f32_16x16x32_bf16(ca, sh, aO[t], 0, 0, 0);
            aO[t] = __builtin_amdgcn_mfma_f32_16x16x32_bf16(ca, sl, aO[t], 0, 0, 0);
        }
    }
    #pragma unroll
    for (int t = 0; t < 4; t++) {
        int p = t * 16 + rr;
        #pragma unroll
        for (int r2 = 0; r2 < 4; r2++) {
            int qq = qb + quad * 4 + r2;
            float y = aD[t][r2] + ea_s[qq] * aO[t][r2] + Dh * b2f(Xt[p][qq]);
            ybuf[(size_t)(b * 1024 + l0 + qq) * 512 + h * 64 + p] = f2b(y);
        }
    }
}

// ---------------- gate: wave-per-row, 16B/lane ----------------
__global__ __launch_bounds__(256) void gate_kernel(const ushort_t* __restrict__ zbuf,
        ushort_t* __restrict__ ybuf, const float* __restrict__ gw) {
    int row = blockIdx.x * 4 + (threadIdx.x >> 6);
    int lane = threadIdx.x & 63;
    size_t base = (size_t)row * 512 + lane * 8;
    short8 zv = *(const short8*)(zbuf + base);
    short8 yv = *(const short8*)(ybuf + base);
    float v[8];
    float ss = 0.f;
    #pragma unroll
    for (int j = 0; j < 8; j++) {
        v[j] = b2f(((ushort_t*)&yv)[j]) * silu_f(b2f(((ushort_t*)&zv)[j]));
        ss += v[j] * v[j];
    }
    #pragma unroll
    for (int o = 1; o < 64; o <<= 1) ss += __shfl_xor(ss, o, 64);
    float rms = rsqrtf(ss * (1.f / 512.f) + 1e-5f);
    float4 g0 = *(const float4*)(gw + lane * 8);
    float4 g1 = *(const float4*)(gw + lane * 8 + 4);
    float gv[8] = {g0.x, g0.y, g0.z, g0.w, g1.x, g1.y, g1.z, g1.w};
    short8 o;
    #pragma unroll
    for (int j = 0; j < 8; j++) ((ushort_t*)&o)[j] = f2b(v[j] * rms * gv[j]);
    *(short8*)(ybuf + base) = o;
}

// ---------------- residual + layernorm: wave-per-row, 16B/lane ----------------
__global__ __launch_bounds__(256) void resln_kernel(float* __restrict__ h,
        ushort_t* __restrict__ hbf, const float* __restrict__ yp,
        const float* __restrict__ g, const float* __restrict__ bb) {
    int row = blockIdx.x * 4 + (threadIdx.x >> 6);
    int lane = threadIdx.x & 63;
    size_t base = (size_t)row * 256 + lane * 4;
    float4 hv = *(const float4*)(h + base);
    float4 yv = *(const float4*)(yp + base);
    float x[4] = {hv.x + yv.x, hv.y + yv.y, hv.z + yv.z, hv.w + yv.w};
    float s = 0.f, s2 = 0.f;
    #pragma unroll
    for (int j = 0; j < 4; j++) { s += x[j]; s2 += x[j] * x[j]; }
    #pragma unroll
    for (int o = 1; o < 64; o <<= 1) { s += __shfl_xor(s, o, 64); s2 += __shfl_xor(s2, o, 64); }
    float mu = s * (1.f / 256.f);
    float var = s2 * (1.f / 256.f) - mu * mu;
    float rstd = rsqrtf(var + 1e-5f);
    float4 gv = *(const float4*)(g + lane * 4);
    float4 bv = *(const float4*)(bb + lane * 4);
    float gr[4] = {gv.x, gv.y, gv.z, gv.w};
    float br[4] = {bv.x, bv.y, bv.z, bv.w};
    float4 ho;
    ushort4_t bo;
    #pragma unroll
    for (int j = 0; j < 4; j++) {
        float o = (x[j] - mu) * rstd * gr[j] + br[j];
        ((float*)&ho)[j] = o;
        bo[j] = f2b(o);
    }
    *(float4*)(h + base) = ho;
    *(ushort4_t*)(hbf + base) = bo;
}

// ---------------- head ----------------
__global__ __launch_bounds__(256) void head_kernel(const float* __restrict__ h,
        const float* __restrict__ hw, const float* __restrict__ stdb,
        const float* __restrict__ meanb, float* __restrict__ out) {
    int blk = blockIdx.x;       // b*192 + t
    int b = blk / 192, t = blk - b * 192;
    int l = 832 + t;
    int tid = threadIdx.x;
    __shared__ float hr[256];
    hr[tid] = h[(size_t)(b * 1024 + l) * 256 + tid];
    __syncthreads();
    if (tid < 21) {
        float acc = 0.f;
        for (int k = 0; k < 256; k++) acc += hr[k] * hw[tid * 256 + k];
        out[(size_t)blk * 21 + tid] = acc * stdb[b * 21 + tid] + meanb[b * 21 + tid];
    }
}

extern "C" void kernel_launch(void* const* d_in, const int* in_sizes, int n_in,
                              void* d_out, int out_size, void* d_ws, size_t ws_size,
                              hipStream_t stream) {
    const float* x_enc  = (const float*)d_in[0];
    const float* x_mark = (const float*)d_in[1];
    const float* tokw   = (const float*)d_in[4];
    const float* tembw  = (const float*)d_in[5];
    const float* ln_g   = (const float*)d_in[6];
    const float* ln_b   = (const float*)d_in[7];
    const float* ipw    = (const float*)d_in[8];
    const float* cw     = (const float*)d_in[9];
    const float* cb     = (const float*)d_in[10];
    const float* dtb    = (const float*)d_in[11];
    const float* alog   = (const float*)d_in[12];
    const float* dsk    = (const float*)d_in[13];
    const float* gw     = (const float*)d_in[14];
    const float* opw    = (const float*)d_in[15];
    const float* hw     = (const float*)d_in[16];
    float* out = (float*)d_out;

    char* w = (char*)d_ws;
    size_t off = 0;
    auto alloc = [&](size_t bytes) -> void* {
        void* p = w + off;
        off += (bytes + 255) & ~(size_t)255;
        return p;
    };
    float* meanb  = (float*)alloc(672 * 4);
    float* stdb   = (float*)alloc(672 * 4);
    float* rstdb  = (float*)alloc(672 * 4);
    float* dts    = (float*)alloc((size_t)262144 * 4);            // 1.05 MB
    float* pebuf  = (float*)alloc((size_t)262144 * 4);            // 1.05 MB
    float* cwt    = (float*)alloc((size_t)10240 * 4);             // 40 KB
    float* hbuf   = (float*)alloc((size_t)8388608 * 4);           // 33.55 MB
    ushort_t* hbf = (ushort_t*)alloc((size_t)8388608 * 2);        // 16.78 MB
    ushort_t* zbuf= (ushort_t*)alloc((size_t)32768 * 512 * 2);    // 33.55 MB
    ushort_t* xc  = (ushort_t*)alloc((size_t)32768 * 640 * 2);    // 41.94 MB
    char* R       = (char*)alloc((size_t)71303168);               // 71.30 MB union
    ushort_t* ybuf= (ushort_t*)alloc((size_t)32768 * 512 * 2);    // 33.55 MB
    ushort_t* wipb= (ushort_t*)alloc((size_t)4 * 1280 * 256 * 2); // 2.62 MB
    ushort_t* wopb= (ushort_t*)alloc((size_t)4 * 256 * 512 * 2);  // 1.05 MB
    // region R aliases: xbuf (gemm_ip out) dies after conv+dt; stbuf/acbuf take over
    ushort_t* xbuf = (ushort_t*)R;                        // 32768 x 704 bf16 = 46.14 MB
    float* stbuf   = (float*)R;                           // 256*16*4096 fp32 = 67.11 MB
    float* acbuf   = (float*)(R + 67108864);              // 256*16*64 fp32 = 4.19 MB
    float* yproj   = (float*)xc;                          // alias: xc dead once gemm_op runs
    (void)ws_size; (void)in_sizes; (void)n_in; (void)out_size;
    // total ~236.5 MB

    stats_kernel<<<672, 256, 0, stream>>>(x_enc, meanb, stdb, rstdb);
    pe_kernel<<<1024, 256, 0, stream>>>(pebuf);
    cvt_pad_ip<<<5120, 256, 0, stream>>>(ipw, wipb);
    cvt_kernel<<<2048, 256, 0, stream>>>(opw, wopb, 524288);
    cvt_convw<<<40, 256, 0, stream>>>(cw, cwt);
    embed3_kernel<<<512, 256, 0, stream>>>(x_enc, x_mark, tokw, tembw, pebuf,
                                           meanb, rstdb, hbuf, hbf);

    for (int layer = 0; layer < 4; layer++) {
        // in_proj: 2560 blocks, linear map, BK=64 (R12 optimum)
        gemm_ip<<<2560, 256, 0, stream>>>(hbf, wipb + (size_t)layer * 1280 * 256,
                                          zbuf, xbuf);
        conv_kernel<<<2560, 256, 0, stream>>>(xbuf, cwt + layer * 2560, cb + layer * 640, xc);
        dt_kernel<<<1024, 256, 0, stream>>>(xbuf, dtb + layer * 8, dts);
        // xbuf now dead -> stbuf/acbuf overwrite region R
        ssd_stateA<<<4096, 256, 0, stream>>>(xc, dts, alog + layer * 8, stbuf, acbuf);
        ssd_scan<<<1024, 256, 0, stream>>>(stbuf, acbuf);
        ssd_outBC<<<4096, 256, 0, stream>>>(xc, dts, acbuf, dsk + layer * 8,
                                            stbuf, ybuf);
        gate_kernel<<<8192, 256, 0, stream>>>(zbuf, ybuf, gw + layer * 512);
        // out_proj: 512 blocks, linear map, BK=64
        gemm_op<<<512, 256, 0, stream>>>(ybuf, wopb + (size_t)layer * 256 * 512, yproj);
        resln_kernel<<<8192, 256, 0, stream>>>(hbuf, hbf, yproj,
                                               ln_g + layer * 256, ln_b + layer * 256);
    }

    head_kernel<<<6144, 256, 0, stream>>>(hbuf, hw, stdb, meanb, out);
}

// Round 17
// 904.558 us; speedup vs baseline: 1.3417x; 1.0330x over previous
//
#include <hip/hip_runtime.h>
#include <hip/hip_bf16.h>

// Model: 4-layer Mamba2 TS model. B=32 L=1024 DM=256 DI=512 DST=64 NH=8 HD=64
// DC=4 Q=64 chunks=16 DIP=1160(pad 1280) CONVD=640 PRED=192 CO=21.
// I/O fp32. bf16 MFMA operands, fp32 accum. WS ~236.5 MB.
// R16->R17: SSD state-traffic cut (268->168 MB/layer): scan writes only
// group-of-4 boundary prefixes into gst (aliases hbf, 16.78MB exact; hbf dead
// between gemm_ip and resln); outBC4 = 1 block per (b,h,grp), keeps running
// state in registers, updates S=ad*S+B_w^T@X in-block (same MFMA as stateA's
// mm3, identical inputs -> bit-identical). Gs LDS reused as Bt after mm2.
// dt merged into conv as whole blocks (grid 2560+128, block-uniform: no R15
// divergence). Ledger: BK=64 GEMM good (47.5us plateau), pipelined dbuf bad,
// dt-in-wave fusion bad, XCD swizzle bad.

typedef unsigned short ushort_t;
typedef unsigned int uint_t;
typedef __attribute__((ext_vector_type(8))) short short8;
typedef __attribute__((ext_vector_type(4))) float f32x4;
typedef __attribute__((ext_vector_type(4))) ushort_t ushort4_t;

__device__ __forceinline__ float b2f(ushort_t u) {
    uint_t v = ((uint_t)u) << 16;
    return __builtin_bit_cast(float, v);
}
__device__ __forceinline__ ushort_t f2b(float f) {
    uint_t u = __builtin_bit_cast(uint_t, f);
    uint_t r = (u + 0x7FFFu + ((u >> 16) & 1u)) >> 16;
    return (ushort_t)r;
}
__device__ __forceinline__ float silu_f(float x) {
    return x / (1.f + __expf(-x));
}
__device__ __forceinline__ void gl_lds16(const ushort_t* g, ushort_t* l) {
    __builtin_amdgcn_global_load_lds(
        (const __attribute__((address_space(1))) unsigned int*)g,
        (__attribute__((address_space(3))) unsigned int*)l, 16, 0, 0);
}

// ---------------- weight converts ----------------
__global__ __launch_bounds__(256) void cvt_kernel(const float* __restrict__ in,
        ushort_t* __restrict__ out, int n) {
    int i = blockIdx.x * 256 + threadIdx.x;
    if (i < n) out[i] = f2b(in[i]);
}
// in_proj w: [4][1160][256] -> bf16 [4][1280][256], rows >=1160 zero
__global__ __launch_bounds__(256) void cvt_pad_ip(const float* __restrict__ in,
        ushort_t* __restrict__ out) {
    int i = blockIdx.x * 256 + threadIdx.x;     // < 4*1280*256
    if (i >= 4 * 1280 * 256) return;
    int layer = i / (1280 * 256);
    int rem = i - layer * 1280 * 256;
    int n = rem >> 8, k = rem & 255;
    out[i] = (n < 1160) ? f2b(in[(size_t)layer * 1160 * 256 + n * 256 + k]) : (ushort_t)0;
}
// conv w: [4][640][4] -> [4][4][640] fp32 transpose
__global__ __launch_bounds__(256) void cvt_convw(const float* __restrict__ in,
        float* __restrict__ out) {
    int i = blockIdx.x * 256 + threadIdx.x;     // < 4*2560
    if (i >= 10240) return;
    int layer = i / 2560;
    int rem = i - layer * 2560;
    int k = rem / 640, ch = rem - k * 640;
    out[i] = in[layer * 2560 + ch * 4 + k];
}

// ---------------- pos-emb table: pe[l][d], computed once ----------------
__global__ __launch_bounds__(256) void pe_kernel(float* __restrict__ pe) {
    int l = blockIdx.x, d = threadIdx.x;
    float div = __expf((float)(d & ~1) * (-9.210340371976184f / 256.0f));
    float arg = (float)l * div;
    pe[l * 256 + d] = (d & 1) ? cosf(arg) : sinf(arg);
}

// ---------------- stats ----------------
__global__ __launch_bounds__(256) void stats_kernel(const float* __restrict__ xe,
        float* __restrict__ meanb, float* __restrict__ stdb, float* __restrict__ rstdb) {
    int bi = blockIdx.x;
    int b = bi / 21, c = bi - b * 21;
    int tid = threadIdx.x;
    float s = 0.f, s2 = 0.f;
    for (int l = tid; l < 1024; l += 256) {
        float v = xe[(b * 1024 + l) * 21 + c];
        s += v; s2 += v * v;
    }
    __shared__ float r1[4], r2[4];
    for (int o = 32; o > 0; o >>= 1) { s += __shfl_down(s, o, 64); s2 += __shfl_down(s2, o, 64); }
    if ((tid & 63) == 0) { r1[tid >> 6] = s; r2[tid >> 6] = s2; }
    __syncthreads();
    if (tid == 0) {
        float S = r1[0] + r1[1] + r1[2] + r1[3];
        float S2 = r2[0] + r2[1] + r2[2] + r2[3];
        float m = S * (1.f / 1024.f);
        float var = S2 * (1.f / 1024.f) - m * m;
        float sd = sqrtf(var + 1e-5f);
        meanb[bi] = m; stdb[bi] = sd; rstdb[bi] = 1.f / sd;
    }
}

// ---------------- embedding: sliding-window, tokw in registers ----------------
__global__ __launch_bounds__(256) void embed3_kernel(const float* __restrict__ xe,
        const float* __restrict__ xm, const float* __restrict__ tokw,
        const float* __restrict__ tembw, const float* __restrict__ pe,
        const float* __restrict__ meanb, const float* __restrict__ rstdb,
        float* __restrict__ h, ushort_t* __restrict__ hbf) {
    int blk = blockIdx.x;               // b*16 + tile
    int b = blk >> 4, t = blk & 15;
    int l0 = t * 64;
    int tid = threadIdx.x;              // = d
    __shared__ float xw[66][22];        // normalized x window, row0 = l0-1 (wrap)
    __shared__ float xmw[64][4];
    __shared__ float mn[21], rs[21];
    if (tid < 21) { mn[tid] = meanb[b * 21 + tid]; rs[tid] = rstdb[b * 21 + tid]; }
    float twr[63];
    {
        const float* tp = tokw + tid * 63;
        #pragma unroll
        for (int i = 0; i < 63; i++) twr[i] = tp[i];
    }
    float tbr[4];
    #pragma unroll
    for (int k = 0; k < 4; k++) tbr[k] = tembw[tid * 4 + k];
    __syncthreads();
    for (int i = tid; i < 1386; i += 256) {
        int row = i / 21, c = i - row * 21;
        int gl = (l0 - 1 + row + 1024) & 1023;
        xw[row][c] = (xe[(size_t)(b * 1024 + gl) * 21 + c] - mn[c]) * rs[c];
    }
    {
        int row = tid >> 2, c = tid & 3;
        xmw[row][c] = xm[(size_t)(b * 1024 + l0 + row) * 4 + c];
    }
    __syncthreads();
    int d = tid;
    float acc2 = 0.f, acc1 = 0.f;   // pending partial sums for out[r-2], out[r-1]
    for (int r = 0; r < 66; r++) {
        float s0 = 0.f, s1 = 0.f, s2 = 0.f;
        #pragma unroll
        for (int c = 0; c < 21; c++) {
            float xv = xw[r][c];
            s0 += xv * twr[c * 3 + 0];
            s1 += xv * twr[c * 3 + 1];
            s2 += xv * twr[c * 3 + 2];
        }
        if (r >= 2) {
            int li = r - 2;
            float acc = acc2 + s2 + pe[(size_t)(l0 + li) * 256 + d];
            #pragma unroll
            for (int k = 0; k < 4; k++) acc += xmw[li][k] * tbr[k];
            size_t o = (size_t)(b * 1024 + l0 + li) * 256 + d;
            h[o] = acc;
            hbf[o] = f2b(acc);
        }
        acc2 = acc1 + s1;
        acc1 = s0;
    }
}

// ---------------- 128x128 LDS-staged GEMM mainloop, BK=64 (2x32 panels) ----------------
template<int KDIM>
__device__ __forceinline__ void gemm128_main(const ushort_t* __restrict__ Ab,
        const ushort_t* __restrict__ Wb, ushort_t* sA, ushort_t* sW,
        f32x4 (&acc)[16], int m0, int n0) {
    int tid = threadIdx.x;
    int w = tid >> 6, lane = tid & 63;
    int wm = w >> 1, wn = w & 1;
    int rr = lane & 15, quad = lane >> 4;
    int srow0 = w * 32 + (lane >> 2);       // staging row (+ j*16)
    int skk = (lane & 3) * 8;               // staging k-offset (shorts)
    int sl0 = w * 1024 + lane * 8;          // staging LDS index (+ j*512, + p*4096)
    for (int k0 = 0; k0 < KDIM; k0 += 64) {
        __syncthreads();                    // prev MFMA reads done before overwrite
        #pragma unroll
        for (int p = 0; p < 2; p++) {
            #pragma unroll
            for (int j = 0; j < 2; j++) {
                int row = srow0 + j * 16;
                int koff = k0 + p * 32 + skk;
                gl_lds16(Ab + (size_t)(m0 + row) * KDIM + koff, &sA[p * 4096 + sl0 + j * 512]);
                gl_lds16(Wb + (size_t)(n0 + row) * KDIM + koff, &sW[p * 4096 + sl0 + j * 512]);
            }
        }
        __syncthreads();                    // compiler drains vmcnt before barrier
        #pragma unroll
        for (int p = 0; p < 2; p++) {
            short8 a[4], b[4];
            #pragma unroll
            for (int i = 0; i < 4; i++)
                a[i] = *(const short8*)&sA[p * 4096 + (wm * 64 + i * 16 + rr) * 32 + quad * 8];
            #pragma unroll
            for (int j = 0; j < 4; j++)
                b[j] = *(const short8*)&sW[p * 4096 + (wn * 64 + j * 16 + rr) * 32 + quad * 8];
            #pragma unroll
            for (int i = 0; i < 4; i++)
                #pragma unroll
                for (int j = 0; j < 4; j++)
                    acc[i * 4 + j] = __builtin_amdgcn_mfma_f32_16x16x32_bf16(a[i], b[j], acc[i * 4 + j], 0, 0, 0);
        }
    }
}

// in_proj: A[32768x256] x W[1280x256] -> split z (n<512) | xBC/dt (512<=n<1160)
__global__ __launch_bounds__(256) void gemm_ip(const ushort_t* __restrict__ A,
        const ushort_t* __restrict__ W, ushort_t* __restrict__ zbuf,
        ushort_t* __restrict__ xbuf) {
    int blk = blockIdx.x;               // 2560 = 256 m-tiles x 10 n-tiles, linear map
    int tm = blk / 10, tn = blk - tm * 10;
    int m0 = tm * 128, n0 = tn * 128;
    __shared__ ushort_t sA[8192], sW[8192];
    f32x4 acc[16];
    #pragma unroll
    for (int i = 0; i < 16; i++) acc[i] = (f32x4){0.f, 0.f, 0.f, 0.f};
    gemm128_main<256>(A, W, sA, sW, acc, m0, n0);
    int lane = threadIdx.x & 63, w = threadIdx.x >> 6;
    int wm = w >> 1, wn = w & 1;
    int rr = lane & 15, quad = lane >> 4;
    #pragma unroll
    for (int i = 0; i < 4; i++) {
        int mrow = m0 + wm * 64 + i * 16 + quad * 4;
        #pragma unroll
        for (int j = 0; j < 4; j++) {
            int n = n0 + wn * 64 + j * 16 + rr;
            #pragma unroll
            for (int r2 = 0; r2 < 4; r2++) {
                ushort_t v = f2b(acc[i * 4 + j][r2]);
                if (n < 512) zbuf[(size_t)(mrow + r2) * 512 + n] = v;
                else if (n < 1160) xbuf[(size_t)(mrow + r2) * 704 + (n - 512)] = v;
            }
        }
    }
}

// out_proj: A[32768x512] x W[256x512] -> C[32768x256] fp32
__global__ __launch_bounds__(256) void gemm_op(const ushort_t* __restrict__ A,
        const ushort_t* __restrict__ W, float* __restrict__ C) {
    int blk = blockIdx.x;               // 512 = 256 m-tiles x 2 n-tiles, linear map
    int tm = blk >> 1, tn = blk & 1;
    int m0 = tm * 128, n0 = tn * 128;
    __shared__ ushort_t sA[8192], sW[8192];
    f32x4 acc[16];
    #pragma unroll
    for (int i = 0; i < 16; i++) acc[i] = (f32x4){0.f, 0.f, 0.f, 0.f};
    gemm128_main<512>(A, W, sA, sW, acc, m0, n0);
    int lane = threadIdx.x & 63, w = threadIdx.x >> 6;
    int wm = w >> 1, wn = w & 1;
    int rr = lane & 15, quad = lane >> 4;
    #pragma unroll
    for (int i = 0; i < 4; i++) {
        int mrow = m0 + wm * 64 + i * 16 + quad * 4;
        #pragma unroll
        for (int j = 0; j < 4; j++) {
            int n = n0 + wn * 64 + j * 16 + rr;
            #pragma unroll
            for (int r2 = 0; r2 < 4; r2++)
                C[(size_t)(mrow + r2) * 256 + n] = acc[i * 4 + j][r2];
        }
    }
}

// ---------------- conv (blocks < 2560) + dt (blocks >= 2560, block-uniform) ----------------
__global__ __launch_bounds__(256) void conv_kernel(const ushort_t* __restrict__ xbuf,
        const float* __restrict__ cwt, const float* __restrict__ cb,
        const float* __restrict__ dtb, ushort_t* __restrict__ xc,
        float* __restrict__ dts) {
    if (blockIdx.x >= 2560) {
        // dt path: whole blocks, no wave divergence. 128 blocks x 256 thr = 32768 rows
        int r = (blockIdx.x - 2560) * 256 + threadIdx.x;
        short8 dv = *(const short8*)(xbuf + (size_t)r * 704 + 640);
        #pragma unroll
        for (int j = 0; j < 8; j++) {
            float x = b2f(((ushort_t*)&dv)[j]) + dtb[j];
            dts[(size_t)r * 8 + j] = (x > 20.f) ? x : log1pf(__expf(x));
        }
        return;
    }
    int idx = blockIdx.x * 256 + threadIdx.x;   // < 8192*80
    int g = idx % 80;
    int rt = idx / 80;
    int ch0 = g * 8;
    int b = rt >> 8;
    int l0 = (rt & 255) << 2;
    float wgt[4][8];
    #pragma unroll
    for (int k = 0; k < 4; k++) {
        float4 w0 = *(const float4*)(cwt + k * 640 + ch0);
        float4 w1 = *(const float4*)(cwt + k * 640 + ch0 + 4);
        wgt[k][0] = w0.x; wgt[k][1] = w0.y; wgt[k][2] = w0.z; wgt[k][3] = w0.w;
        wgt[k][4] = w1.x; wgt[k][5] = w1.y; wgt[k][6] = w1.z; wgt[k][7] = w1.w;
    }
    float bias[8];
    {
        float4 b0 = *(const float4*)(cb + ch0);
        float4 b1 = *(const float4*)(cb + ch0 + 4);
        bias[0] = b0.x; bias[1] = b0.y; bias[2] = b0.z; bias[3] = b0.w;
        bias[4] = b1.x; bias[5] = b1.y; bias[6] = b1.z; bias[7] = b1.w;
    }
    short8 xr[7];
    const ushort_t* base = xbuf + (size_t)(b * 1024 + l0) * 704 + ch0;
    #pragma unroll
    for (int i = 0; i < 7; i++) {
        int ll = l0 - 3 + i;
        if (ll >= 0) xr[i] = *(const short8*)(base + (ptrdiff_t)(i - 3) * 704);
        else         xr[i] = (short8){0, 0, 0, 0, 0, 0, 0, 0};
    }
    #pragma unroll
    for (int lo = 0; lo < 4; lo++) {
        float acc[8];
        #pragma unroll
        for (int j = 0; j < 8; j++) acc[j] = bias[j];
        #pragma unroll
        for (int k = 0; k < 4; k++) {
            #pragma unroll
            for (int j = 0; j < 8; j++)
                acc[j] += b2f(((ushort_t*)&xr[lo + k])[j]) * wgt[k][j];
        }
        short8 o;
        #pragma unroll
        for (int j = 0; j < 8; j++) ((ushort_t*)&o)[j] = f2b(silu_f(acc[j]));
        *(short8*)(xc + (size_t)(b * 1024 + l0 + lo) * 640 + ch0) = o;
    }
}

// ---------------- SSD A: chunk states = (B*dec)^T @ X per (b,h,chunk) ----------------
__global__ __launch_bounds__(256) void ssd_stateA(const ushort_t* __restrict__ xc,
        const float* __restrict__ dts, const float* __restrict__ alog,
        float* __restrict__ stbuf, float* __restrict__ acbuf) {
    int idx = blockIdx.x;               // bh*16 + chunk
    int bh = idx >> 4, chunk = idx & 15;
    int b = bh >> 3, h = bh & 7;
    int l0 = chunk * 64;
    float Ah = -__expf(alog[h]);
    int tid = threadIdx.x;
    int q = tid >> 2, pb = (tid & 3) * 16;

    __shared__ ushort_t Bt[64][72], Xt[64][72];
    __shared__ float dec_s[64];

    const ushort_t* xrow = xc + (size_t)(b * 1024 + l0 + q) * 640;
    ushort_t bv[16], xv[16];
    *(short8*)&bv[0] = *(const short8*)(xrow + 512 + pb);
    *(short8*)&bv[8] = *(const short8*)(xrow + 512 + pb + 8);
    *(short8*)&xv[0] = *(const short8*)(xrow + h * 64 + pb);
    *(short8*)&xv[8] = *(const short8*)(xrow + h * 64 + pb + 8);
    #pragma unroll
    for (int j = 0; j < 16; j++) Xt[pb + j][q] = xv[j];

    if (tid < 64) {
        float d = dts[(size_t)(b * 1024 + l0 + tid) * 8 + h];
        float a = d * Ah;
        #pragma unroll
        for (int off = 1; off < 64; off <<= 1) {
            float t = __shfl_up(a, off, 64);
            if (tid >= off) a += t;
        }
        acbuf[(size_t)idx * 64 + tid] = a;
        float tot = __shfl(a, 63, 64);
        dec_s[tid] = __expf(tot - a) * d;
    }
    __syncthreads();
    {
        float dq = dec_s[q];
        #pragma unroll
        for (int j = 0; j < 16; j++) Bt[pb + j][q] = f2b(b2f(bv[j]) * dq);
    }
    __syncthreads();

    int w = tid >> 6, lane = tid & 63;
    int rr = lane & 15, quad = lane >> 4, qb = w * 16;
    f32x4 acc[4];
    #pragma unroll
    for (int t = 0; t < 4; t++) acc[t] = (f32x4){0.f, 0.f, 0.f, 0.f};
    #pragma unroll
    for (int ks = 0; ks < 2; ks++) {
        short8 a = *(const short8*)(&Bt[qb + rr][ks * 32 + quad * 8]);
        #pragma unroll
        for (int t = 0; t < 4; t++) {
            short8 bb = *(const short8*)(&Xt[t * 16 + rr][ks * 32 + quad * 8]);
            acc[t] = __builtin_amdgcn_mfma_f32_16x16x32_bf16(a, bb, acc[t], 0, 0, 0);
        }
    }
    float* sb = stbuf + (size_t)idx * 4096;
    #pragma unroll
    for (int t = 0; t < 4; t++) {
        int p = t * 16 + rr;
        #pragma unroll
        for (int r2 = 0; r2 < 4; r2++) {
            int nn = qb + quad * 4 + r2;
            sb[nn * 64 + p] = acc[t][r2];
        }
    }
}

// ---------------- SSD B: scan chunk states -> group-boundary prefixes (4-way split) ----------------
__global__ __launch_bounds__(256) void ssd_scan(const float* __restrict__ stbuf,
        const float* __restrict__ acbuf, float* __restrict__ gst) {
    int bh = blockIdx.x >> 2, sl = blockIdx.x & 3;
    int tid = threadIdx.x;
    size_t boff = (size_t)sl * 1024 + tid * 4;
    float4 S = make_float4(0.f, 0.f, 0.f, 0.f);
    for (int c = 0; c < 16; c++) {
        if ((c & 3) == 0)
            *(float4*)(gst + (size_t)(bh * 4 + (c >> 2)) * 4096 + boff) = S;
        const float* p = stbuf + ((size_t)bh * 16 + c) * 4096 + boff;
        float ad = __expf(acbuf[((size_t)bh * 16 + c) * 64 + 63]);
        float4 v = *(const float4*)p;
        S.x = ad * S.x + v.x; S.y = ad * S.y + v.y;
        S.z = ad * S.z + v.z; S.w = ad * S.w + v.w;
    }
}

// ---------------- SSD C: per (b,h,group-of-4): y = Y_diag + Y_off + D*x, in-block state ----------------
__global__ __launch_bounds__(256) void ssd_outBC4(const ushort_t* __restrict__ xc,
        const float* __restrict__ dts, const float* __restrict__ acbuf,
        const float* __restrict__ dsk, const float* __restrict__ gst,
        ushort_t* __restrict__ ybuf) {
    int idx = blockIdx.x;               // 1024 = bh*4 + grp
    int bh = idx >> 2, grp = idx & 3;
    int b = bh >> 3, h = bh & 7;
    float Dh = dsk[h];
    int tid = threadIdx.x;
    int q = tid >> 2, pb = (tid & 3) * 16;
    int w = tid >> 6, lane = tid & 63;
    int rr = lane & 15, quad = lane >> 4, qb = w * 16;

    // Gs doubles as the Bt tile after mm2 reads complete
    __shared__ ushort_t Cs[64][72], Bs[64][72], Xt[64][72], Gs[64][72], Shi[64][72], Slo[64][72];
    __shared__ float acum_s[64], dtq_s[64], ea_s[64], dec_s[64];
    __shared__ float ad_sh;

    // running prefix state S, C/D layout: row nn=qb+quad*4+r2, col p=t*16+rr
    float S[4][4];
    {
        const float* s0 = gst + (size_t)idx * 4096;
        #pragma unroll
        for (int t = 0; t < 4; t++) {
            int p = t * 16 + rr;
            #pragma unroll
            for (int r2 = 0; r2 < 4; r2++)
                S[t][r2] = s0[(qb + quad * 4 + r2) * 64 + p];
        }
    }

    for (int c4 = 0; c4 < 4; c4++) {
        int chunk = grp * 4 + c4;
        int l0 = chunk * 64;
        size_t cidx = (size_t)bh * 16 + chunk;
        const ushort_t* xrow = xc + (size_t)(b * 1024 + l0 + q) * 640;
        *(short8*)&Bs[q][pb]     = *(const short8*)(xrow + 512 + pb);
        *(short8*)&Bs[q][pb + 8] = *(const short8*)(xrow + 512 + pb + 8);
        *(short8*)&Cs[q][pb]     = *(const short8*)(xrow + 576 + pb);
        *(short8*)&Cs[q][pb + 8] = *(const short8*)(xrow + 576 + pb + 8);
        ushort_t xv[16];
        *(short8*)&xv[0] = *(const short8*)(xrow + h * 64 + pb);
        *(short8*)&xv[8] = *(const short8*)(xrow + h * 64 + pb + 8);
        #pragma unroll
        for (int j = 0; j < 16; j++) Xt[pb + j][q] = xv[j];
        if (tid < 64) {
            float a = acbuf[cidx * 64 + tid];
            acum_s[tid] = a;
            ea_s[tid] = __expf(a);
            float d = dts[(size_t)(b * 1024 + l0 + tid) * 8 + h];
            dtq_s[tid] = d;
            float tot = acbuf[cidx * 64 + 63];
            dec_s[tid] = __expf(tot - a) * d;
            if (tid == 0) ad_sh = __expf(tot);
        }
        // Shi/Slo from S registers (A-operand layout [p][n])
        #pragma unroll
        for (int t = 0; t < 4; t++) {
            int p = t * 16 + rr;
            #pragma unroll
            for (int r2 = 0; r2 < 4; r2++) {
                float s = S[t][r2];
                ushort_t hi = f2b(s);
                Shi[p][qb + quad * 4 + r2] = hi;
                Slo[p][qb + quad * 4 + r2] = f2b(s - b2f(hi));
            }
        }
        __syncthreads();    // b1: tiles + state + scalars ready

        // mm1: G = C.B^T masked -> Gs bf16
        {
            f32x4 g[4];
            #pragma unroll
            for (int t = 0; t < 4; t++) g[t] = (f32x4){0.f, 0.f, 0.f, 0.f};
            #pragma unroll
            for (int ks = 0; ks < 2; ks++) {
                short8 a = *(const short8*)(&Cs[qb + rr][ks * 32 + quad * 8]);
                #pragma unroll
                for (int t = 0; t < 4; t++) {
                    short8 bb = *(const short8*)(&Bs[t * 16 + rr][ks * 32 + quad * 8]);
                    g[t] = __builtin_amdgcn_mfma_f32_16x16x32_bf16(a, bb, g[t], 0, 0, 0);
                }
            }
            #pragma unroll
            for (int t = 0; t < 4; t++) {
                int s = t * 16 + rr;
                float as = acum_s[s], dss = dtq_s[s];
                #pragma unroll
                for (int r2 = 0; r2 < 4; r2++) {
                    int qq = qb + quad * 4 + r2;
                    float v = (s <= qq) ? g[t][r2] * __expf(acum_s[qq] - as) * dss : 0.f;
                    Gs[qq][s] = f2b(v);
                }
            }
        }
        __syncthreads();    // b2

        // mm2: Y_diag = G@X ; Y_off = C@(Shi+Slo)
        f32x4 aD[4], aO[4];
        #pragma unroll
        for (int t = 0; t < 4; t++) { aD[t] = (f32x4){0.f,0.f,0.f,0.f}; aO[t] = (f32x4){0.f,0.f,0.f,0.f}; }
        #pragma unroll
        for (int ks = 0; ks < 2; ks++) {
            short8 ga = *(const short8*)(&Gs[qb + rr][ks * 32 + quad * 8]);
            short8 ca = *(const short8*)(&Cs[qb + rr][ks * 32 + quad * 8]);
            #pragma unroll
            for (int t = 0; t < 4; t++) {
                short8 xb = *(const short8*)(&Xt[t * 16 + rr][ks * 32 + quad * 8]);
                short8 sh = *(const short8*)(&Shi[t * 16 + rr][ks * 32 + quad * 8]);
                short8 sl = *(const short8*)(&Slo[t * 16 + rr][ks * 32 + quad * 8]);
                aD[t] = __builtin_amdgcn_mfma_f32_16x16x32_bf16(ga, xb, aD[t], 0, 0, 0);
                aO[t] = __builtin_amdgcn_mfma_f32_16x16x32_bf16(ca, sh, aO[t], 0, 0, 0);
                aO[t] = __builtin_amdgcn_mfma_f32_16x16x32_bf16(ca, sl, aO[t], 0, 0, 0);
            }
        }
        #pragma unroll
        for (int t = 0; t < 4; t++) {
            int p = t * 16 + rr;
            #pragma unroll
            for (int r2 = 0; r2 < 4; r2++) {
                int qq = qb + quad * 4 + r2;
                float y = aD[t][r2] + ea_s[qq] * aO[t][r2] + Dh * b2f(Xt[p][qq]);
                ybuf[(size_t)(b * 1024 + l0 + qq) * 512 + h * 64 + p] = f2b(y);
            }
        }
        __syncthreads();    // b3: Gs reads done -> reuse as Bt

        // Bt = B*dec in [n][q] layout, into Gs storage
        {
            float dq = dec_s[q];
            #pragma unroll
            for (int j = 0; j < 16; j++)
                Gs[pb + j][q] = f2b(b2f(Bs[q][pb + j]) * dq);
        }
        __syncthreads();    // b4

        // state update: S = ad*S + Bt^T @ X (identical MFMA to stateA's mm3)
        {
            f32x4 acc[4];
            #pragma unroll
            for (int t = 0; t < 4; t++) acc[t] = (f32x4){0.f, 0.f, 0.f, 0.f};
            #pragma unroll
            for (int ks = 0; ks < 2; ks++) {
                short8 a = *(const short8*)(&Gs[qb + rr][ks * 32 + quad * 8]);
                #pragma unroll
                for (int t = 0; t < 4; t++) {
                    short8 bb = *(const short8*)(&Xt[t * 16 + rr][ks * 32 + quad * 8]);
                    acc[t] = __builtin_amdgcn_mfma_f32_16x16x32_bf16(a, bb, acc[t], 0, 0, 0);
                }
            }
            float ad = ad_sh;
            #pragma unroll
            for (int t = 0; t < 4; t++)
                #pragma unroll
                for (int r2 = 0; r2 < 4; r2++)
                    S[t][r2] = ad * S[t][r2] + acc[t][r2];
        }
        __syncthreads();    // b5: loop-end, protect tile overwrite
    }
}

// ---------------- gate: wave-per-row, 16B/lane ----------------
__global__ __launch_bounds__(256) void gate_kernel(const ushort_t* __restrict__ zbuf,
        ushort_t* __restrict__ ybuf, const float* __restrict__ gw) {
    int row = blockIdx.x * 4 + (threadIdx.x >> 6);
    int lane = threadIdx.x & 63;
    size_t base = (size_t)row * 512 + lane * 8;
    short8 zv = *(const short8*)(zbuf + base);
    short8 yv = *(const short8*)(ybuf + base);
    float v[8];
    float ss = 0.f;
    #pragma unroll
    for (int j = 0; j < 8; j++) {
        v[j] = b2f(((ushort_t*)&yv)[j]) * silu_f(b2f(((ushort_t*)&zv)[j]));
        ss += v[j] * v[j];
    }
    #pragma unroll
    for (int o = 1; o < 64; o <<= 1) ss += __shfl_xor(ss, o, 64);
    float rms = rsqrtf(ss * (1.f / 512.f) + 1e-5f);
    float4 g0 = *(const float4*)(gw + lane * 8);
    float4 g1 = *(const float4*)(gw + lane * 8 + 4);
    float gv[8] = {g0.x, g0.y, g0.z, g0.w, g1.x, g1.y, g1.z, g1.w};
    short8 o;
    #pragma unroll
    for (int j = 0; j < 8; j++) ((ushort_t*)&o)[j] = f2b(v[j] * rms * gv[j]);
    *(short8*)(ybuf + base) = o;
}

// ---------------- residual + layernorm: wave-per-row, 16B/lane ----------------
__global__ __launch_bounds__(256) void resln_kernel(float* __restrict__ h,
        ushort_t* __restrict__ hbf, const float* __restrict__ yp,
        const float* __restrict__ g, const float* __restrict__ bb) {
    int row = blockIdx.x * 4 + (threadIdx.x >> 6);
    int lane = threadIdx.x & 63;
    size_t base = (size_t)row * 256 + lane * 4;
    float4 hv = *(const float4*)(h + base);
    float4 yv = *(const float4*)(yp + base);
    float x[4] = {hv.x + yv.x, hv.y + yv.y, hv.z + yv.z, hv.w + yv.w};
    float s = 0.f, s2 = 0.f;
    #pragma unroll
    for (int j = 0; j < 4; j++) { s += x[j]; s2 += x[j] * x[j]; }
    #pragma unroll
    for (int o = 1; o < 64; o <<= 1) { s += __shfl_xor(s, o, 64); s2 += __shfl_xor(s2, o, 64); }
    float mu = s * (1.f / 256.f);
    float var = s2 * (1.f / 256.f) - mu * mu;
    float rstd = rsqrtf(var + 1e-5f);
    float4 gv = *(const float4*)(g + lane * 4);
    float4 bv = *(const float4*)(bb + lane * 4);
    float gr[4] = {gv.x, gv.y, gv.z, gv.w};
    float br[4] = {bv.x, bv.y, bv.z, bv.w};
    float4 ho;
    ushort4_t bo;
    #pragma unroll
    for (int j = 0; j < 4; j++) {
        float o = (x[j] - mu) * rstd * gr[j] + br[j];
        ((float*)&ho)[j] = o;
        bo[j] = f2b(o);
    }
    *(float4*)(h + base) = ho;
    *(ushort4_t*)(hbf + base) = bo;
}

// ---------------- head ----------------
__global__ __launch_bounds__(256) void head_kernel(const float* __restrict__ h,
        const float* __restrict__ hw, const float* __restrict__ stdb,
        const float* __restrict__ meanb, float* __restrict__ out) {
    int blk = blockIdx.x;       // b*192 + t
    int b = blk / 192, t = blk - b * 192;
    int l = 832 + t;
    int tid = threadIdx.x;
    __shared__ float hr[256];
    hr[tid] = h[(size_t)(b * 1024 + l) * 256 + tid];
    __syncthreads();
    if (tid < 21) {
        float acc = 0.f;
        for (int k = 0; k < 256; k++) acc += hr[k] * hw[tid * 256 + k];
        out[(size_t)blk * 21 + tid] = acc * stdb[b * 21 + tid] + meanb[b * 21 + tid];
    }
}

extern "C" void kernel_launch(void* const* d_in, const int* in_sizes, int n_in,
                              void* d_out, int out_size, void* d_ws, size_t ws_size,
                              hipStream_t stream) {
    const float* x_enc  = (const float*)d_in[0];
    const float* x_mark = (const float*)d_in[1];
    const float* tokw   = (const float*)d_in[4];
    const float* tembw  = (const float*)d_in[5];
    const float* ln_g   = (const float*)d_in[6];
    const float* ln_b   = (const float*)d_in[7];
    const float* ipw    = (const float*)d_in[8];
    const float* cw     = (const float*)d_in[9];
    const float* cb     = (const float*)d_in[10];
    const float* dtb    = (const float*)d_in[11];
    const float* alog   = (const float*)d_in[12];
    const float* dsk    = (const float*)d_in[13];
    const float* gw     = (const float*)d_in[14];
    const float* opw    = (const float*)d_in[15];
    const float* hw     = (const float*)d_in[16];
    float* out = (float*)d_out;

    char* w = (char*)d_ws;
    size_t off = 0;
    auto alloc = [&](size_t bytes) -> void* {
        void* p = w + off;
        off += (bytes + 255) & ~(size_t)255;
        return p;
    };
    float* meanb  = (float*)alloc(672 * 4);
    float* stdb   = (float*)alloc(672 * 4);
    float* rstdb  = (float*)alloc(672 * 4);
    float* dts    = (float*)alloc((size_t)262144 * 4);            // 1.05 MB
    float* pebuf  = (float*)alloc((size_t)262144 * 4);            // 1.05 MB
    float* cwt    = (float*)alloc((size_t)10240 * 4);             // 40 KB
    float* hbuf   = (float*)alloc((size_t)8388608 * 4);           // 33.55 MB
    ushort_t* hbf = (ushort_t*)alloc((size_t)8388608 * 2);        // 16.78 MB
    ushort_t* zbuf= (ushort_t*)alloc((size_t)32768 * 512 * 2);    // 33.55 MB
    ushort_t* xc  = (ushort_t*)alloc((size_t)32768 * 640 * 2);    // 41.94 MB
    char* R       = (char*)alloc((size_t)71303168);               // 71.30 MB union
    ushort_t* ybuf= (ushort_t*)alloc((size_t)32768 * 512 * 2);    // 33.55 MB
    ushort_t* wipb= (ushort_t*)alloc((size_t)4 * 1280 * 256 * 2); // 2.62 MB
    ushort_t* wopb= (ushort_t*)alloc((size_t)4 * 256 * 512 * 2);  // 1.05 MB
    // region R aliases: xbuf (gemm_ip out) dies after conv+dt; stbuf/acbuf take over
    ushort_t* xbuf = (ushort_t*)R;                        // 32768 x 704 bf16 = 46.14 MB
    float* stbuf   = (float*)R;                           // 256*16*4096 fp32 = 67.11 MB
    float* acbuf   = (float*)(R + 67108864);              // 256*16*64 fp32 = 4.19 MB
    float* yproj   = (float*)xc;                          // alias: xc dead once gemm_op runs
    // gst aliases hbf (both exactly 16,777,216 B): hbf consumed by gemm_ip
    // before scan writes gst; resln rewrites hbf after outBC4 reads gst.
    float* gst     = (float*)hbf;                         // 1024 x 4096 fp32
    (void)ws_size; (void)in_sizes; (void)n_in; (void)out_size;
    // total ~236.5 MB

    stats_kernel<<<672, 256, 0, stream>>>(x_enc, meanb, stdb, rstdb);
    pe_kernel<<<1024, 256, 0, stream>>>(pebuf);
    cvt_pad_ip<<<5120, 256, 0, stream>>>(ipw, wipb);
    cvt_kernel<<<2048, 256, 0, stream>>>(opw, wopb, 524288);
    cvt_convw<<<40, 256, 0, stream>>>(cw, cwt);
    embed3_kernel<<<512, 256, 0, stream>>>(x_enc, x_mark, tokw, tembw, pebuf,
                                           meanb, rstdb, hbuf, hbf);

    for (int layer = 0; layer < 4; layer++) {
        // in_proj: 2560 blocks, linear map, BK=64 (R12 optimum); reads hbf
        gemm_ip<<<2560, 256, 0, stream>>>(hbf, wipb + (size_t)layer * 1280 * 256,
                                          zbuf, xbuf);
        // conv (2560 blocks) + dt (128 blocks), block-uniform split
        conv_kernel<<<2688, 256, 0, stream>>>(xbuf, cwt + layer * 2560,
                                              cb + layer * 640, dtb + layer * 8,
                                              xc, dts);
        // xbuf now dead -> stbuf/acbuf overwrite region R
        ssd_stateA<<<4096, 256, 0, stream>>>(xc, dts, alog + layer * 8, stbuf, acbuf);
        ssd_scan<<<1024, 256, 0, stream>>>(stbuf, acbuf, gst);   // writes gst (=hbf region)
        ssd_outBC4<<<1024, 256, 0, stream>>>(xc, dts, acbuf, dsk + layer * 8,
                                             gst, ybuf);
        gate_kernel<<<8192, 256, 0, stream>>>(zbuf, ybuf, gw + layer * 512);
        // out_proj: 512 blocks, linear map, BK=64
        gemm_op<<<512, 256, 0, stream>>>(ybuf, wopb + (size_t)layer * 256 * 512, yproj);
        // resln rewrites hbf (clobbers dead gst) for next layer's gemm_ip
        resln_kernel<<<8192, 256, 0, stream>>>(hbuf, hbf, yproj,
                                               ln_g + layer * 256, ln_b + layer * 256);
    }

    head_kernel<<<6144, 256, 0, stream>>>(hbuf, hw, stdb, meanb, out);
}

// Round 18
// 878.214 us; speedup vs baseline: 1.3820x; 1.0300x over previous
//
#include <hip/hip_runtime.h>
#include <hip/hip_bf16.h>

// Model: 4-layer Mamba2 TS model. B=32 L=1024 DM=256 DI=512 DST=64 NH=8 HD=64
// DC=4 Q=64 chunks=16 DIP=1160(pad 1280) CONVD=640 PRED=192 CO=21.
// I/O fp32. bf16 MFMA operands, fp32 accum. WS ~236.5 MB.
// R17->R18: stateA -> stateA4 (block per (b,h,grp), 4 chunks sequential,
// group-partial T=ad*T+state_c in registers -> writes 17MB not 67MB); scan
// group-level (S=Ag*S+T_g, Ag=prod exp(tot_c)): stbuf traffic 168->68MB/layer.
// Group0/1 prefixes bit-identical; 2/3 differ ~1e-7 rel (Ag association),
// absorbed by bf16 hi/lo split. Ledger: BK=64 GEMM 47.5us plateau; pipelined
// dbuf bad; dt-in-wave fusion bad; XCD swizzle bad; R17 outBC4 good (-30us).

typedef unsigned short ushort_t;
typedef unsigned int uint_t;
typedef __attribute__((ext_vector_type(8))) short short8;
typedef __attribute__((ext_vector_type(4))) float f32x4;
typedef __attribute__((ext_vector_type(4))) ushort_t ushort4_t;

__device__ __forceinline__ float b2f(ushort_t u) {
    uint_t v = ((uint_t)u) << 16;
    return __builtin_bit_cast(float, v);
}
__device__ __forceinline__ ushort_t f2b(float f) {
    uint_t u = __builtin_bit_cast(uint_t, f);
    uint_t r = (u + 0x7FFFu + ((u >> 16) & 1u)) >> 16;
    return (ushort_t)r;
}
__device__ __forceinline__ float silu_f(float x) {
    return x / (1.f + __expf(-x));
}
__device__ __forceinline__ void gl_lds16(const ushort_t* g, ushort_t* l) {
    __builtin_amdgcn_global_load_lds(
        (const __attribute__((address_space(1))) unsigned int*)g,
        (__attribute__((address_space(3))) unsigned int*)l, 16, 0, 0);
}

// ---------------- weight converts ----------------
__global__ __launch_bounds__(256) void cvt_kernel(const float* __restrict__ in,
        ushort_t* __restrict__ out, int n) {
    int i = blockIdx.x * 256 + threadIdx.x;
    if (i < n) out[i] = f2b(in[i]);
}
// in_proj w: [4][1160][256] -> bf16 [4][1280][256], rows >=1160 zero
__global__ __launch_bounds__(256) void cvt_pad_ip(const float* __restrict__ in,
        ushort_t* __restrict__ out) {
    int i = blockIdx.x * 256 + threadIdx.x;     // < 4*1280*256
    if (i >= 4 * 1280 * 256) return;
    int layer = i / (1280 * 256);
    int rem = i - layer * 1280 * 256;
    int n = rem >> 8, k = rem & 255;
    out[i] = (n < 1160) ? f2b(in[(size_t)layer * 1160 * 256 + n * 256 + k]) : (ushort_t)0;
}
// conv w: [4][640][4] -> [4][4][640] fp32 transpose
__global__ __launch_bounds__(256) void cvt_convw(const float* __restrict__ in,
        float* __restrict__ out) {
    int i = blockIdx.x * 256 + threadIdx.x;     // < 4*2560
    if (i >= 10240) return;
    int layer = i / 2560;
    int rem = i - layer * 2560;
    int k = rem / 640, ch = rem - k * 640;
    out[i] = in[layer * 2560 + ch * 4 + k];
}

// ---------------- pos-emb table: pe[l][d], computed once ----------------
__global__ __launch_bounds__(256) void pe_kernel(float* __restrict__ pe) {
    int l = blockIdx.x, d = threadIdx.x;
    float div = __expf((float)(d & ~1) * (-9.210340371976184f / 256.0f));
    float arg = (float)l * div;
    pe[l * 256 + d] = (d & 1) ? cosf(arg) : sinf(arg);
}

// ---------------- stats ----------------
__global__ __launch_bounds__(256) void stats_kernel(const float* __restrict__ xe,
        float* __restrict__ meanb, float* __restrict__ stdb, float* __restrict__ rstdb) {
    int bi = blockIdx.x;
    int b = bi / 21, c = bi - b * 21;
    int tid = threadIdx.x;
    float s = 0.f, s2 = 0.f;
    for (int l = tid; l < 1024; l += 256) {
        float v = xe[(b * 1024 + l) * 21 + c];
        s += v; s2 += v * v;
    }
    __shared__ float r1[4], r2[4];
    for (int o = 32; o > 0; o >>= 1) { s += __shfl_down(s, o, 64); s2 += __shfl_down(s2, o, 64); }
    if ((tid & 63) == 0) { r1[tid >> 6] = s; r2[tid >> 6] = s2; }
    __syncthreads();
    if (tid == 0) {
        float S = r1[0] + r1[1] + r1[2] + r1[3];
        float S2 = r2[0] + r2[1] + r2[2] + r2[3];
        float m = S * (1.f / 1024.f);
        float var = S2 * (1.f / 1024.f) - m * m;
        float sd = sqrtf(var + 1e-5f);
        meanb[bi] = m; stdb[bi] = sd; rstdb[bi] = 1.f / sd;
    }
}

// ---------------- embedding: sliding-window, tokw in registers ----------------
__global__ __launch_bounds__(256) void embed3_kernel(const float* __restrict__ xe,
        const float* __restrict__ xm, const float* __restrict__ tokw,
        const float* __restrict__ tembw, const float* __restrict__ pe,
        const float* __restrict__ meanb, const float* __restrict__ rstdb,
        float* __restrict__ h, ushort_t* __restrict__ hbf) {
    int blk = blockIdx.x;               // b*16 + tile
    int b = blk >> 4, t = blk & 15;
    int l0 = t * 64;
    int tid = threadIdx.x;              // = d
    __shared__ float xw[66][22];        // normalized x window, row0 = l0-1 (wrap)
    __shared__ float xmw[64][4];
    __shared__ float mn[21], rs[21];
    if (tid < 21) { mn[tid] = meanb[b * 21 + tid]; rs[tid] = rstdb[b * 21 + tid]; }
    float twr[63];
    {
        const float* tp = tokw + tid * 63;
        #pragma unroll
        for (int i = 0; i < 63; i++) twr[i] = tp[i];
    }
    float tbr[4];
    #pragma unroll
    for (int k = 0; k < 4; k++) tbr[k] = tembw[tid * 4 + k];
    __syncthreads();
    for (int i = tid; i < 1386; i += 256) {
        int row = i / 21, c = i - row * 21;
        int gl = (l0 - 1 + row + 1024) & 1023;
        xw[row][c] = (xe[(size_t)(b * 1024 + gl) * 21 + c] - mn[c]) * rs[c];
    }
    {
        int row = tid >> 2, c = tid & 3;
        xmw[row][c] = xm[(size_t)(b * 1024 + l0 + row) * 4 + c];
    }
    __syncthreads();
    int d = tid;
    float acc2 = 0.f, acc1 = 0.f;   // pending partial sums for out[r-2], out[r-1]
    for (int r = 0; r < 66; r++) {
        float s0 = 0.f, s1 = 0.f, s2 = 0.f;
        #pragma unroll
        for (int c = 0; c < 21; c++) {
            float xv = xw[r][c];
            s0 += xv * twr[c * 3 + 0];
            s1 += xv * twr[c * 3 + 1];
            s2 += xv * twr[c * 3 + 2];
        }
        if (r >= 2) {
            int li = r - 2;
            float acc = acc2 + s2 + pe[(size_t)(l0 + li) * 256 + d];
            #pragma unroll
            for (int k = 0; k < 4; k++) acc += xmw[li][k] * tbr[k];
            size_t o = (size_t)(b * 1024 + l0 + li) * 256 + d;
            h[o] = acc;
            hbf[o] = f2b(acc);
        }
        acc2 = acc1 + s1;
        acc1 = s0;
    }
}

// ---------------- 128x128 LDS-staged GEMM mainloop, BK=64 (2x32 panels) ----------------
template<int KDIM>
__device__ __forceinline__ void gemm128_main(const ushort_t* __restrict__ Ab,
        const ushort_t* __restrict__ Wb, ushort_t* sA, ushort_t* sW,
        f32x4 (&acc)[16], int m0, int n0) {
    int tid = threadIdx.x;
    int w = tid >> 6, lane = tid & 63;
    int wm = w >> 1, wn = w & 1;
    int rr = lane & 15, quad = lane >> 4;
    int srow0 = w * 32 + (lane >> 2);       // staging row (+ j*16)
    int skk = (lane & 3) * 8;               // staging k-offset (shorts)
    int sl0 = w * 1024 + lane * 8;          // staging LDS index (+ j*512, + p*4096)
    for (int k0 = 0; k0 < KDIM; k0 += 64) {
        __syncthreads();                    // prev MFMA reads done before overwrite
        #pragma unroll
        for (int p = 0; p < 2; p++) {
            #pragma unroll
            for (int j = 0; j < 2; j++) {
                int row = srow0 + j * 16;
                int koff = k0 + p * 32 + skk;
                gl_lds16(Ab + (size_t)(m0 + row) * KDIM + koff, &sA[p * 4096 + sl0 + j * 512]);
                gl_lds16(Wb + (size_t)(n0 + row) * KDIM + koff, &sW[p * 4096 + sl0 + j * 512]);
            }
        }
        __syncthreads();                    // compiler drains vmcnt before barrier
        #pragma unroll
        for (int p = 0; p < 2; p++) {
            short8 a[4], b[4];
            #pragma unroll
            for (int i = 0; i < 4; i++)
                a[i] = *(const short8*)&sA[p * 4096 + (wm * 64 + i * 16 + rr) * 32 + quad * 8];
            #pragma unroll
            for (int j = 0; j < 4; j++)
                b[j] = *(const short8*)&sW[p * 4096 + (wn * 64 + j * 16 + rr) * 32 + quad * 8];
            #pragma unroll
            for (int i = 0; i < 4; i++)
                #pragma unroll
                for (int j = 0; j < 4; j++)
                    acc[i * 4 + j] = __builtin_amdgcn_mfma_f32_16x16x32_bf16(a[i], b[j], acc[i * 4 + j], 0, 0, 0);
        }
    }
}

// in_proj: A[32768x256] x W[1280x256] -> split z (n<512) | xBC/dt (512<=n<1160)
__global__ __launch_bounds__(256) void gemm_ip(const ushort_t* __restrict__ A,
        const ushort_t* __restrict__ W, ushort_t* __restrict__ zbuf,
        ushort_t* __restrict__ xbuf) {
    int blk = blockIdx.x;               // 2560 = 256 m-tiles x 10 n-tiles, linear map
    int tm = blk / 10, tn = blk - tm * 10;
    int m0 = tm * 128, n0 = tn * 128;
    __shared__ ushort_t sA[8192], sW[8192];
    f32x4 acc[16];
    #pragma unroll
    for (int i = 0; i < 16; i++) acc[i] = (f32x4){0.f, 0.f, 0.f, 0.f};
    gemm128_main<256>(A, W, sA, sW, acc, m0, n0);
    int lane = threadIdx.x & 63, w = threadIdx.x >> 6;
    int wm = w >> 1, wn = w & 1;
    int rr = lane & 15, quad = lane >> 4;
    #pragma unroll
    for (int i = 0; i < 4; i++) {
        int mrow = m0 + wm * 64 + i * 16 + quad * 4;
        #pragma unroll
        for (int j = 0; j < 4; j++) {
            int n = n0 + wn * 64 + j * 16 + rr;
            #pragma unroll
            for (int r2 = 0; r2 < 4; r2++) {
                ushort_t v = f2b(acc[i * 4 + j][r2]);
                if (n < 512) zbuf[(size_t)(mrow + r2) * 512 + n] = v;
                else if (n < 1160) xbuf[(size_t)(mrow + r2) * 704 + (n - 512)] = v;
            }
        }
    }
}

// out_proj: A[32768x512] x W[256x512] -> C[32768x256] fp32
__global__ __launch_bounds__(256) void gemm_op(const ushort_t* __restrict__ A,
        const ushort_t* __restrict__ W, float* __restrict__ C) {
    int blk = blockIdx.x;               // 512 = 256 m-tiles x 2 n-tiles, linear map
    int tm = blk >> 1, tn = blk & 1;
    int m0 = tm * 128, n0 = tn * 128;
    __shared__ ushort_t sA[8192], sW[8192];
    f32x4 acc[16];
    #pragma unroll
    for (int i = 0; i < 16; i++) acc[i] = (f32x4){0.f, 0.f, 0.f, 0.f};
    gemm128_main<512>(A, W, sA, sW, acc, m0, n0);
    int lane = threadIdx.x & 63, w = threadIdx.x >> 6;
    int wm = w >> 1, wn = w & 1;
    int rr = lane & 15, quad = lane >> 4;
    #pragma unroll
    for (int i = 0; i < 4; i++) {
        int mrow = m0 + wm * 64 + i * 16 + quad * 4;
        #pragma unroll
        for (int j = 0; j < 4; j++) {
            int n = n0 + wn * 64 + j * 16 + rr;
            #pragma unroll
            for (int r2 = 0; r2 < 4; r2++)
                C[(size_t)(mrow + r2) * 256 + n] = acc[i * 4 + j][r2];
        }
    }
}

// ---------------- conv (blocks < 2560) + dt (blocks >= 2560, block-uniform) ----------------
__global__ __launch_bounds__(256) void conv_kernel(const ushort_t* __restrict__ xbuf,
        const float* __restrict__ cwt, const float* __restrict__ cb,
        const float* __restrict__ dtb, ushort_t* __restrict__ xc,
        float* __restrict__ dts) {
    if (blockIdx.x >= 2560) {
        int r = (blockIdx.x - 2560) * 256 + threadIdx.x;
        short8 dv = *(const short8*)(xbuf + (size_t)r * 704 + 640);
        #pragma unroll
        for (int j = 0; j < 8; j++) {
            float x = b2f(((ushort_t*)&dv)[j]) + dtb[j];
            dts[(size_t)r * 8 + j] = (x > 20.f) ? x : log1pf(__expf(x));
        }
        return;
    }
    int idx = blockIdx.x * 256 + threadIdx.x;   // < 8192*80
    int g = idx % 80;
    int rt = idx / 80;
    int ch0 = g * 8;
    int b = rt >> 8;
    int l0 = (rt & 255) << 2;
    float wgt[4][8];
    #pragma unroll
    for (int k = 0; k < 4; k++) {
        float4 w0 = *(const float4*)(cwt + k * 640 + ch0);
        float4 w1 = *(const float4*)(cwt + k * 640 + ch0 + 4);
        wgt[k][0] = w0.x; wgt[k][1] = w0.y; wgt[k][2] = w0.z; wgt[k][3] = w0.w;
        wgt[k][4] = w1.x; wgt[k][5] = w1.y; wgt[k][6] = w1.z; wgt[k][7] = w1.w;
    }
    float bias[8];
    {
        float4 b0 = *(const float4*)(cb + ch0);
        float4 b1 = *(const float4*)(cb + ch0 + 4);
        bias[0] = b0.x; bias[1] = b0.y; bias[2] = b0.z; bias[3] = b0.w;
        bias[4] = b1.x; bias[5] = b1.y; bias[6] = b1.z; bias[7] = b1.w;
    }
    short8 xr[7];
    const ushort_t* base = xbuf + (size_t)(b * 1024 + l0) * 704 + ch0;
    #pragma unroll
    for (int i = 0; i < 7; i++) {
        int ll = l0 - 3 + i;
        if (ll >= 0) xr[i] = *(const short8*)(base + (ptrdiff_t)(i - 3) * 704);
        else         xr[i] = (short8){0, 0, 0, 0, 0, 0, 0, 0};
    }
    #pragma unroll
    for (int lo = 0; lo < 4; lo++) {
        float acc[8];
        #pragma unroll
        for (int j = 0; j < 8; j++) acc[j] = bias[j];
        #pragma unroll
        for (int k = 0; k < 4; k++) {
            #pragma unroll
            for (int j = 0; j < 8; j++)
                acc[j] += b2f(((ushort_t*)&xr[lo + k])[j]) * wgt[k][j];
        }
        short8 o;
        #pragma unroll
        for (int j = 0; j < 8; j++) ((ushort_t*)&o)[j] = f2b(silu_f(acc[j]));
        *(short8*)(xc + (size_t)(b * 1024 + l0 + lo) * 640 + ch0) = o;
    }
}

// ---------------- SSD A4: group-partial states per (b,h,grp), 4 chunks in-block ----------------
// T = ad_c*T + (B*dec)^T@X per chunk (same recurrence & MFMAs as old stateA+scan)
__global__ __launch_bounds__(256) void ssd_stateA4(const ushort_t* __restrict__ xc,
        const float* __restrict__ dts, const float* __restrict__ alog,
        float* __restrict__ stbuf, float* __restrict__ acbuf) {
    int idx = blockIdx.x;               // 1024 = bh*4 + grp
    int bh = idx >> 2, grp = idx & 3;
    int b = bh >> 3, h = bh & 7;
    float Ah = -__expf(alog[h]);
    int tid = threadIdx.x;
    int q = tid >> 2, pb = (tid & 3) * 16;
    int w = tid >> 6, lane = tid & 63;
    int rr = lane & 15, quad = lane >> 4, qb = w * 16;

    __shared__ ushort_t Bt[64][72], Xt[64][72];
    __shared__ float dec_s[64];
    __shared__ float ad_sh;

    float T[4][4];
    #pragma unroll
    for (int t = 0; t < 4; t++)
        #pragma unroll
        for (int r2 = 0; r2 < 4; r2++) T[t][r2] = 0.f;

    for (int c4 = 0; c4 < 4; c4++) {
        int chunk = grp * 4 + c4;
        int l0 = chunk * 64;
        size_t cidx = (size_t)bh * 16 + chunk;
        const ushort_t* xrow = xc + (size_t)(b * 1024 + l0 + q) * 640;
        ushort_t bv[16], xv[16];
        *(short8*)&bv[0] = *(const short8*)(xrow + 512 + pb);
        *(short8*)&bv[8] = *(const short8*)(xrow + 512 + pb + 8);
        *(short8*)&xv[0] = *(const short8*)(xrow + h * 64 + pb);
        *(short8*)&xv[8] = *(const short8*)(xrow + h * 64 + pb + 8);
        #pragma unroll
        for (int j = 0; j < 16; j++) Xt[pb + j][q] = xv[j];

        if (tid < 64) {
            float d = dts[(size_t)(b * 1024 + l0 + tid) * 8 + h];
            float a = d * Ah;
            #pragma unroll
            for (int off = 1; off < 64; off <<= 1) {
                float t = __shfl_up(a, off, 64);
                if (tid >= off) a += t;
            }
            acbuf[cidx * 64 + tid] = a;
            float tot = __shfl(a, 63, 64);
            dec_s[tid] = __expf(tot - a) * d;
            if (tid == 0) ad_sh = __expf(tot);
        }
        __syncthreads();    // b1: Xt + dec_s + ad_sh ready
        {
            float dq = dec_s[q];
            #pragma unroll
            for (int j = 0; j < 16; j++) Bt[pb + j][q] = f2b(b2f(bv[j]) * dq);
        }
        __syncthreads();    // b2: Bt ready

        f32x4 acc[4];
        #pragma unroll
        for (int t = 0; t < 4; t++) acc[t] = (f32x4){0.f, 0.f, 0.f, 0.f};
        #pragma unroll
        for (int ks = 0; ks < 2; ks++) {
            short8 a = *(const short8*)(&Bt[qb + rr][ks * 32 + quad * 8]);
            #pragma unroll
            for (int t = 0; t < 4; t++) {
                short8 bb = *(const short8*)(&Xt[t * 16 + rr][ks * 32 + quad * 8]);
                acc[t] = __builtin_amdgcn_mfma_f32_16x16x32_bf16(a, bb, acc[t], 0, 0, 0);
            }
        }
        {
            float ad = ad_sh;
            #pragma unroll
            for (int t = 0; t < 4; t++)
                #pragma unroll
                for (int r2 = 0; r2 < 4; r2++)
                    T[t][r2] = ad * T[t][r2] + acc[t][r2];
        }
        __syncthreads();    // b3: tile reads done before next-iter overwrite
    }
    float* sb = stbuf + (size_t)idx * 4096;     // [n][p] layout
    #pragma unroll
    for (int t = 0; t < 4; t++) {
        int p = t * 16 + rr;
        #pragma unroll
        for (int r2 = 0; r2 < 4; r2++)
            sb[(qb + quad * 4 + r2) * 64 + p] = T[t][r2];
    }
}

// ---------------- SSD B: group-level scan -> group-boundary prefixes ----------------
__global__ __launch_bounds__(256) void ssd_scan(const float* __restrict__ stbuf,
        const float* __restrict__ acbuf, float* __restrict__ gst) {
    int bh = blockIdx.x >> 2, sl = blockIdx.x & 3;
    int tid = threadIdx.x;
    size_t boff = (size_t)sl * 1024 + tid * 4;
    float4 S = make_float4(0.f, 0.f, 0.f, 0.f);
    for (int g = 0; g < 4; g++) {
        *(float4*)(gst + (size_t)(bh * 4 + g) * 4096 + boff) = S;
        float Ag = 1.f;
        #pragma unroll
        for (int c = 0; c < 4; c++)
            Ag *= __expf(acbuf[((size_t)bh * 16 + g * 4 + c) * 64 + 63]);
        float4 v = *(const float4*)(stbuf + (size_t)(bh * 4 + g) * 4096 + boff);
        S.x = Ag * S.x + v.x; S.y = Ag * S.y + v.y;
        S.z = Ag * S.z + v.z; S.w = Ag * S.w + v.w;
    }
}

// ---------------- SSD C: per (b,h,group-of-4): y = Y_diag + Y_off + D*x, in-block state ----------------
__global__ __launch_bounds__(256) void ssd_outBC4(const ushort_t* __restrict__ xc,
        const float* __restrict__ dts, const float* __restrict__ acbuf,
        const float* __restrict__ dsk, const float* __restrict__ gst,
        ushort_t* __restrict__ ybuf) {
    int idx = blockIdx.x;               // 1024 = bh*4 + grp
    int bh = idx >> 2, grp = idx & 3;
    int b = bh >> 3, h = bh & 7;
    float Dh = dsk[h];
    int tid = threadIdx.x;
    int q = tid >> 2, pb = (tid & 3) * 16;
    int w = tid >> 6, lane = tid & 63;
    int rr = lane & 15, quad = lane >> 4, qb = w * 16;

    // Gs doubles as the Bt tile after mm2 reads complete
    __shared__ ushort_t Cs[64][72], Bs[64][72], Xt[64][72], Gs[64][72], Shi[64][72], Slo[64][72];
    __shared__ float acum_s[64], dtq_s[64], ea_s[64], dec_s[64];
    __shared__ float ad_sh;

    // running prefix state S, C/D layout: row nn=qb+quad*4+r2, col p=t*16+rr
    float S[4][4];
    {
        const float* s0 = gst + (size_t)idx * 4096;
        #pragma unroll
        for (int t = 0; t < 4; t++) {
            int p = t * 16 + rr;
            #pragma unroll
            for (int r2 = 0; r2 < 4; r2++)
                S[t][r2] = s0[(qb + quad * 4 + r2) * 64 + p];
        }
    }

    for (int c4 = 0; c4 < 4; c4++) {
        int chunk = grp * 4 + c4;
        int l0 = chunk * 64;
        size_t cidx = (size_t)bh * 16 + chunk;
        const ushort_t* xrow = xc + (size_t)(b * 1024 + l0 + q) * 640;
        *(short8*)&Bs[q][pb]     = *(const short8*)(xrow + 512 + pb);
        *(short8*)&Bs[q][pb + 8] = *(const short8*)(xrow + 512 + pb + 8);
        *(short8*)&Cs[q][pb]     = *(const short8*)(xrow + 576 + pb);
        *(short8*)&Cs[q][pb + 8] = *(const short8*)(xrow + 576 + pb + 8);
        ushort_t xv[16];
        *(short8*)&xv[0] = *(const short8*)(xrow + h * 64 + pb);
        *(short8*)&xv[8] = *(const short8*)(xrow + h * 64 + pb + 8);
        #pragma unroll
        for (int j = 0; j < 16; j++) Xt[pb + j][q] = xv[j];
        if (tid < 64) {
            float a = acbuf[cidx * 64 + tid];
            acum_s[tid] = a;
            ea_s[tid] = __expf(a);
            float d = dts[(size_t)(b * 1024 + l0 + tid) * 8 + h];
            dtq_s[tid] = d;
            float tot = acbuf[cidx * 64 + 63];
            dec_s[tid] = __expf(tot - a) * d;
            if (tid == 0) ad_sh = __expf(tot);
        }
        // Shi/Slo from S registers (A-operand layout [p][n])
        #pragma unroll
        for (int t = 0; t < 4; t++) {
            int p = t * 16 + rr;
            #pragma unroll
            for (int r2 = 0; r2 < 4; r2++) {
                float s = S[t][r2];
                ushort_t hi = f2b(s);
                Shi[p][qb + quad * 4 + r2] = hi;
                Slo[p][qb + quad * 4 + r2] = f2b(s - b2f(hi));
            }
        }
        __syncthreads();    // b1: tiles + state + scalars ready

        // mm1: G = C.B^T masked -> Gs bf16
        {
            f32x4 g[4];
            #pragma unroll
            for (int t = 0; t < 4; t++) g[t] = (f32x4){0.f, 0.f, 0.f, 0.f};
            #pragma unroll
            for (int ks = 0; ks < 2; ks++) {
                short8 a = *(const short8*)(&Cs[qb + rr][ks * 32 + quad * 8]);
                #pragma unroll
                for (int t = 0; t < 4; t++) {
                    short8 bb = *(const short8*)(&Bs[t * 16 + rr][ks * 32 + quad * 8]);
                    g[t] = __builtin_amdgcn_mfma_f32_16x16x32_bf16(a, bb, g[t], 0, 0, 0);
                }
            }
            #pragma unroll
            for (int t = 0; t < 4; t++) {
                int s = t * 16 + rr;
                float as = acum_s[s], dss = dtq_s[s];
                #pragma unroll
                for (int r2 = 0; r2 < 4; r2++) {
                    int qq = qb + quad * 4 + r2;
                    float v = (s <= qq) ? g[t][r2] * __expf(acum_s[qq] - as) * dss : 0.f;
                    Gs[qq][s] = f2b(v);
                }
            }
        }
        __syncthreads();    // b2

        // mm2: Y_diag = G@X ; Y_off = C@(Shi+Slo)
        f32x4 aD[4], aO[4];
        #pragma unroll
        for (int t = 0; t < 4; t++) { aD[t] = (f32x4){0.f,0.f,0.f,0.f}; aO[t] = (f32x4){0.f,0.f,0.f,0.f}; }
        #pragma unroll
        for (int ks = 0; ks < 2; ks++) {
            short8 ga = *(const short8*)(&Gs[qb + rr][ks * 32 + quad * 8]);
            short8 ca = *(const short8*)(&Cs[qb + rr][ks * 32 + quad * 8]);
            #pragma unroll
            for (int t = 0; t < 4; t++) {
                short8 xb = *(const short8*)(&Xt[t * 16 + rr][ks * 32 + quad * 8]);
                short8 sh = *(const short8*)(&Shi[t * 16 + rr][ks * 32 + quad * 8]);
                short8 sl = *(const short8*)(&Slo[t * 16 + rr][ks * 32 + quad * 8]);
                aD[t] = __builtin_amdgcn_mfma_f32_16x16x32_bf16(ga, xb, aD[t], 0, 0, 0);
                aO[t] = __builtin_amdgcn_mfma_f32_16x16x32_bf16(ca, sh, aO[t], 0, 0, 0);
                aO[t] = __builtin_amdgcn_mfma_f32_16x16x32_bf16(ca, sl, aO[t], 0, 0, 0);
            }
        }
        #pragma unroll
        for (int t = 0; t < 4; t++) {
            int p = t * 16 + rr;
            #pragma unroll
            for (int r2 = 0; r2 < 4; r2++) {
                int qq = qb + quad * 4 + r2;
                float y = aD[t][r2] + ea_s[qq] * aO[t][r2] + Dh * b2f(Xt[p][qq]);
                ybuf[(size_t)(b * 1024 + l0 + qq) * 512 + h * 64 + p] = f2b(y);
            }
        }
        __syncthreads();    // b3: Gs reads done -> reuse as Bt

        // Bt = B*dec in [n][q] layout, into Gs storage
        {
            float dq = dec_s[q];
            #pragma unroll
            for (int j = 0; j < 16; j++)
                Gs[pb + j][q] = f2b(b2f(Bs[q][pb + j]) * dq);
        }
        __syncthreads();    // b4

        // state update: S = ad*S + Bt^T @ X (identical MFMA to stateA4)
        {
            f32x4 acc[4];
            #pragma unroll
            for (int t = 0; t < 4; t++) acc[t] = (f32x4){0.f, 0.f, 0.f, 0.f};
            #pragma unroll
            for (int ks = 0; ks < 2; ks++) {
                short8 a = *(const short8*)(&Gs[qb + rr][ks * 32 + quad * 8]);
                #pragma unroll
                for (int t = 0; t < 4; t++) {
                    short8 bb = *(const short8*)(&Xt[t * 16 + rr][ks * 32 + quad * 8]);
                    acc[t] = __builtin_amdgcn_mfma_f32_16x16x32_bf16(a, bb, acc[t], 0, 0, 0);
                }
            }
            float ad = ad_sh;
            #pragma unroll
            for (int t = 0; t < 4; t++)
                #pragma unroll
                for (int r2 = 0; r2 < 4; r2++)
                    S[t][r2] = ad * S[t][r2] + acc[t][r2];
        }
        __syncthreads();    // b5: loop-end, protect tile overwrite
    }
}

// ---------------- gate: wave-per-row, 16B/lane ----------------
__global__ __launch_bounds__(256) void gate_kernel(const ushort_t* __restrict__ zbuf,
        ushort_t* __restrict__ ybuf, const float* __restrict__ gw) {
    int row = blockIdx.x * 4 + (threadIdx.x >> 6);
    int lane = threadIdx.x & 63;
    size_t base = (size_t)row * 512 + lane * 8;
    short8 zv = *(const short8*)(zbuf + base);
    short8 yv = *(const short8*)(ybuf + base);
    float v[8];
    float ss = 0.f;
    #pragma unroll
    for (int j = 0; j < 8; j++) {
        v[j] = b2f(((ushort_t*)&yv)[j]) * silu_f(b2f(((ushort_t*)&zv)[j]));
        ss += v[j] * v[j];
    }
    #pragma unroll
    for (int o = 1; o < 64; o <<= 1) ss += __shfl_xor(ss, o, 64);
    float rms = rsqrtf(ss * (1.f / 512.f) + 1e-5f);
    float4 g0 = *(const float4*)(gw + lane * 8);
    float4 g1 = *(const float4*)(gw + lane * 8 + 4);
    float gv[8] = {g0.x, g0.y, g0.z, g0.w, g1.x, g1.y, g1.z, g1.w};
    short8 o;
    #pragma unroll
    for (int j = 0; j < 8; j++) ((ushort_t*)&o)[j] = f2b(v[j] * rms * gv[j]);
    *(short8*)(ybuf + base) = o;
}

// ---------------- residual + layernorm: wave-per-row, 16B/lane ----------------
__global__ __launch_bounds__(256) void resln_kernel(float* __restrict__ h,
        ushort_t* __restrict__ hbf, const float* __restrict__ yp,
        const float* __restrict__ g, const float* __restrict__ bb) {
    int row = blockIdx.x * 4 + (threadIdx.x >> 6);
    int lane = threadIdx.x & 63;
    size_t base = (size_t)row * 256 + lane * 4;
    float4 hv = *(const float4*)(h + base);
    float4 yv = *(const float4*)(yp + base);
    float x[4] = {hv.x + yv.x, hv.y + yv.y, hv.z + yv.z, hv.w + yv.w};
    float s = 0.f, s2 = 0.f;
    #pragma unroll
    for (int j = 0; j < 4; j++) { s += x[j]; s2 += x[j] * x[j]; }
    #pragma unroll
    for (int o = 1; o < 64; o <<= 1) { s += __shfl_xor(s, o, 64); s2 += __shfl_xor(s2, o, 64); }
    float mu = s * (1.f / 256.f);
    float var = s2 * (1.f / 256.f) - mu * mu;
    float rstd = rsqrtf(var + 1e-5f);
    float4 gv = *(const float4*)(g + lane * 4);
    float4 bv = *(const float4*)(bb + lane * 4);
    float gr[4] = {gv.x, gv.y, gv.z, gv.w};
    float br[4] = {bv.x, bv.y, bv.z, bv.w};
    float4 ho;
    ushort4_t bo;
    #pragma unroll
    for (int j = 0; j < 4; j++) {
        float o = (x[j] - mu) * rstd * gr[j] + br[j];
        ((float*)&ho)[j] = o;
        bo[j] = f2b(o);
    }
    *(float4*)(h + base) = ho;
    *(ushort4_t*)(hbf + base) = bo;
}

// ---------------- head ----------------
__global__ __launch_bounds__(256) void head_kernel(const float* __restrict__ h,
        const float* __restrict__ hw, const float* __restrict__ stdb,
        const float* __restrict__ meanb, float* __restrict__ out) {
    int blk = blockIdx.x;       // b*192 + t
    int b = blk / 192, t = blk - b * 192;
    int l = 832 + t;
    int tid = threadIdx.x;
    __shared__ float hr[256];
    hr[tid] = h[(size_t)(b * 1024 + l) * 256 + tid];
    __syncthreads();
    if (tid < 21) {
        float acc = 0.f;
        for (int k = 0; k < 256; k++) acc += hr[k] * hw[tid * 256 + k];
        out[(size_t)blk * 21 + tid] = acc * stdb[b * 21 + tid] + meanb[b * 21 + tid];
    }
}

extern "C" void kernel_launch(void* const* d_in, const int* in_sizes, int n_in,
                              void* d_out, int out_size, void* d_ws, size_t ws_size,
                              hipStream_t stream) {
    const float* x_enc  = (const float*)d_in[0];
    const float* x_mark = (const float*)d_in[1];
    const float* tokw   = (const float*)d_in[4];
    const float* tembw  = (const float*)d_in[5];
    const float* ln_g   = (const float*)d_in[6];
    const float* ln_b   = (const float*)d_in[7];
    const float* ipw    = (const float*)d_in[8];
    const float* cw     = (const float*)d_in[9];
    const float* cb     = (const float*)d_in[10];
    const float* dtb    = (const float*)d_in[11];
    const float* alog   = (const float*)d_in[12];
    const float* dsk    = (const float*)d_in[13];
    const float* gw     = (const float*)d_in[14];
    const float* opw    = (const float*)d_in[15];
    const float* hw     = (const float*)d_in[16];
    float* out = (float*)d_out;

    char* w = (char*)d_ws;
    size_t off = 0;
    auto alloc = [&](size_t bytes) -> void* {
        void* p = w + off;
        off += (bytes + 255) & ~(size_t)255;
        return p;
    };
    float* meanb  = (float*)alloc(672 * 4);
    float* stdb   = (float*)alloc(672 * 4);
    float* rstdb  = (float*)alloc(672 * 4);
    float* dts    = (float*)alloc((size_t)262144 * 4);            // 1.05 MB
    float* pebuf  = (float*)alloc((size_t)262144 * 4);            // 1.05 MB
    float* cwt    = (float*)alloc((size_t)10240 * 4);             // 40 KB
    float* hbuf   = (float*)alloc((size_t)8388608 * 4);           // 33.55 MB
    ushort_t* hbf = (ushort_t*)alloc((size_t)8388608 * 2);        // 16.78 MB
    ushort_t* zbuf= (ushort_t*)alloc((size_t)32768 * 512 * 2);    // 33.55 MB
    ushort_t* xc  = (ushort_t*)alloc((size_t)32768 * 640 * 2);    // 41.94 MB
    char* R       = (char*)alloc((size_t)71303168);               // 71.30 MB union
    ushort_t* ybuf= (ushort_t*)alloc((size_t)32768 * 512 * 2);    // 33.55 MB
    ushort_t* wipb= (ushort_t*)alloc((size_t)4 * 1280 * 256 * 2); // 2.62 MB
    ushort_t* wopb= (ushort_t*)alloc((size_t)4 * 256 * 512 * 2);  // 1.05 MB
    // region R aliases: xbuf (gemm_ip out) dies after conv+dt; stbuf/acbuf take over
    ushort_t* xbuf = (ushort_t*)R;                        // 32768 x 704 bf16 = 46.14 MB
    float* stbuf   = (float*)R;                           // 1024 x 4096 fp32 = 16.78 MB (group partials)
    float* acbuf   = (float*)(R + 67108864);              // 256*16*64 fp32 = 4.19 MB
    float* yproj   = (float*)xc;                          // alias: xc dead once gemm_op runs
    // gst aliases hbf (both exactly 16,777,216 B): hbf consumed by gemm_ip
    // before scan writes gst; resln rewrites hbf after outBC4 reads gst.
    float* gst     = (float*)hbf;                         // 1024 x 4096 fp32
    (void)ws_size; (void)in_sizes; (void)n_in; (void)out_size;
    // total ~236.5 MB

    stats_kernel<<<672, 256, 0, stream>>>(x_enc, meanb, stdb, rstdb);
    pe_kernel<<<1024, 256, 0, stream>>>(pebuf);
    cvt_pad_ip<<<5120, 256, 0, stream>>>(ipw, wipb);
    cvt_kernel<<<2048, 256, 0, stream>>>(opw, wopb, 524288);
    cvt_convw<<<40, 256, 0, stream>>>(cw, cwt);
    embed3_kernel<<<512, 256, 0, stream>>>(x_enc, x_mark, tokw, tembw, pebuf,
                                           meanb, rstdb, hbuf, hbf);

    for (int layer = 0; layer < 4; layer++) {
        // in_proj: 2560 blocks, linear map, BK=64 (R12 optimum); reads hbf
        gemm_ip<<<2560, 256, 0, stream>>>(hbf, wipb + (size_t)layer * 1280 * 256,
                                          zbuf, xbuf);
        // conv (2560 blocks) + dt (128 blocks), block-uniform split
        conv_kernel<<<2688, 256, 0, stream>>>(xbuf, cwt + layer * 2560,
                                              cb + layer * 640, dtb + layer * 8,
                                              xc, dts);
        // xbuf now dead -> stbuf/acbuf overwrite region R
        ssd_stateA4<<<1024, 256, 0, stream>>>(xc, dts, alog + layer * 8, stbuf, acbuf);
        ssd_scan<<<1024, 256, 0, stream>>>(stbuf, acbuf, gst);   // writes gst (=hbf region)
        ssd_outBC4<<<1024, 256, 0, stream>>>(xc, dts, acbuf, dsk + layer * 8,
                                             gst, ybuf);
        gate_kernel<<<8192, 256, 0, stream>>>(zbuf, ybuf, gw + layer * 512);
        // out_proj: 512 blocks, linear map, BK=64
        gemm_op<<<512, 256, 0, stream>>>(ybuf, wopb + (size_t)layer * 256 * 512, yproj);
        // resln rewrites hbf (clobbers dead gst) for next layer's gemm_ip
        resln_kernel<<<8192, 256, 0, stream>>>(hbuf, hbf, yproj,
                                               ln_g + layer * 256, ln_b + layer * 256);
    }

    head_kernel<<<6144, 256, 0, stream>>>(hbuf, hw, stdb, meanb, out);
}